// Round 2
// baseline (1105.296 us; speedup 1.0000x reference)
//
#include <hip/hip_runtime.h>

#define ROI 268
#define NG 512
#define NNODES (NG * ROI)   // 137216
#define CH 32
#define SLOPE 0.33f
#define BN_EPS 1e-5f
#define SA 34               // bufA row stride (words): even -> b64-aligned rows
#define SB 33               // bufB row stride (words)

__device__ __forceinline__ float leakyf(float v) {
    return v > 0.f ? v : SLOPE * v;
}

// native ds_add_f32 (no CAS loop, no return value -> fire-and-forget)
__device__ __forceinline__ void lds_fadd(float* p, float v) {
    __hip_atomic_fetch_add(p, v, __ATOMIC_RELAXED, __HIP_MEMORY_SCOPE_WORKGROUP);
}

// ---------------------------------------------------------------------------
// K1: y0[N,32] = x[N,268] @ W1_0[268,32]   (fp32 vector GEMM)
// ---------------------------------------------------------------------------
__global__ __launch_bounds__(256, 2) void k_gemm1(
    const float* __restrict__ x, const float* __restrict__ W1,
    float* __restrict__ y0) {
    __shared__ float sW[ROI * CH];
    __shared__ float sA[32 * 260];

    const int tid = threadIdx.x;
    const size_t rowbase = (size_t)blockIdx.x * 256;

    for (int i = tid; i < (ROI * CH) / 4; i += 256)
        ((float4*)sW)[i] = ((const float4*)W1)[i];

    float acc[4][8];
#pragma unroll
    for (int r = 0; r < 4; r++)
#pragma unroll
        for (int c = 0; c < 8; c++) acc[r][c] = 0.f;

    const int rg = tid >> 2;
    const int cg = tid & 3;

    int k0 = 0;
    for (int chunk = 0; chunk < 9; ++chunk) {
        const int ksize = (chunk < 8) ? 32 : 12;
        __syncthreads();
        const int nf4 = (ksize >> 2) << 8;
        for (int f = tid; f < nf4; f += 256) {
            int row, kk;
            if (ksize == 32) { row = f >> 3; kk = (f & 7) << 2; }
            else             { row = f & 255; kk = (f >> 8) << 2; }
            float4 v = *(const float4*)&x[(rowbase + row) * ROI + k0 + kk];
            sA[(kk + 0) * 260 + row] = v.x;
            sA[(kk + 1) * 260 + row] = v.y;
            sA[(kk + 2) * 260 + row] = v.z;
            sA[(kk + 3) * 260 + row] = v.w;
        }
        __syncthreads();
#pragma unroll 4
        for (int kk = 0; kk < ksize; ++kk) {
            float4 a4 = *(float4*)&sA[kk * 260 + rg * 4];
            const float* wr = &sW[(k0 + kk) * CH + cg * 8];
            float4 w0 = *(const float4*)wr;
            float4 w1 = *(const float4*)(wr + 4);
            float av[4] = {a4.x, a4.y, a4.z, a4.w};
            float wv[8] = {w0.x, w0.y, w0.z, w0.w, w1.x, w1.y, w1.z, w1.w};
#pragma unroll
            for (int r = 0; r < 4; r++)
#pragma unroll
                for (int c = 0; c < 8; c++) acc[r][c] += av[r] * wv[c];
        }
        k0 += ksize;
    }

#pragma unroll
    for (int r = 0; r < 4; r++) {
        size_t row = rowbase + rg * 4 + r;
        *(float4*)&y0[row * CH + cg * 8] =
            make_float4(acc[r][0], acc[r][1], acc[r][2], acc[r][3]);
        *(float4*)&y0[row * CH + cg * 8 + 4] =
            make_float4(acc[r][4], acc[r][5], acc[r][6], acc[r][7]);
    }
}

// ---------------------------------------------------------------------------
// K2: bucket edges by graph
// ---------------------------------------------------------------------------
__global__ void k_hist(const int* __restrict__ dst, int E, int* __restrict__ cnt) {
    __shared__ int h[NG];
    for (int i = threadIdx.x; i < NG; i += blockDim.x) h[i] = 0;
    __syncthreads();
    int stride = gridDim.x * blockDim.x;
    for (int i = blockIdx.x * blockDim.x + threadIdx.x; i < E; i += stride)
        atomicAdd(&h[dst[i] / ROI], 1);
    __syncthreads();
    for (int i = threadIdx.x; i < NG; i += blockDim.x)
        if (h[i]) atomicAdd(&cnt[i], h[i]);
}

__global__ void k_scan(const int* __restrict__ cnt, int* __restrict__ off,
                       int* __restrict__ cur) {
    __shared__ int s[NG];
    int t = threadIdx.x;   // 512 threads
    int myc = cnt[t];
    s[t] = myc;
    __syncthreads();
    for (int d = 1; d < NG; d <<= 1) {
        int v = (t >= d) ? s[t - d] : 0;
        __syncthreads();
        s[t] += v;
        __syncthreads();
    }
    int inc = s[t];
    int exc = inc - myc;
    off[t] = exc;
    cur[t * 16] = exc;              // padded: one counter per 64B line
    if (t == NG - 1) off[NG] = inc;
}

__global__ void k_scatter(const int* __restrict__ src, const int* __restrict__ dst,
                          int E, int* __restrict__ cur, int* __restrict__ packed) {
    int stride = gridDim.x * blockDim.x;
    for (int i = blockIdx.x * blockDim.x + threadIdx.x; i < E; i += stride) {
        int d = dst[i];
        int g = d / ROI;
        int s_ = src[i];
        int pos = atomicAdd(&cur[g * 16], 1);
        // pre-multiplied LDS word offsets: low16 = srcLocal*SA, high16 = dstLocal*SB
        packed[pos] = ((s_ - g * ROI) * SA) | (((d - g * ROI) * SB) << 16);
    }
}

// ---------------------------------------------------------------------------
// K3 helpers
// ---------------------------------------------------------------------------
__device__ __forceinline__ void edge_agg(const float* __restrict__ bufA,
                                         float* __restrict__ bufB,
                                         const int* __restrict__ ep, int nE,
                                         int t) {
    const int ch = t & 31;
    const int slot = t >> 5;   // 0..15
    int i = slot;
    for (; i + 48 < nE; i += 64) {
        int p0 = ep[i], p1 = ep[i + 16], p2 = ep[i + 32], p3 = ep[i + 48];
        float v0 = bufA[(p0 & 0xffff) + ch];
        float v1 = bufA[(p1 & 0xffff) + ch];
        float v2 = bufA[(p2 & 0xffff) + ch];
        float v3 = bufA[(p3 & 0xffff) + ch];
        lds_fadd(&bufB[(p0 >> 16) + ch], v0);
        lds_fadd(&bufB[(p1 >> 16) + ch], v1);
        lds_fadd(&bufB[(p2 >> 16) + ch], v2);
        lds_fadd(&bufB[(p3 >> 16) + ch], v3);
    }
    for (; i < nE; i += 16) {
        int p = ep[i];
        lds_fadd(&bufB[(p >> 16) + ch], bufA[(p & 0xffff) + ch]);
    }
}

// in-place row-local GEMM: buf[268 rows, stride SA] <- act(buf @ w)
// unit = row-pair (134) x col-quarter (4) = 536 units over 512 threads.
// iter-1 touches rows 0..255 only, iter-2 rows 256..267 only -> no overlap;
// within a row-pair all 4 units live in one wave (lockstep: reads before writes).
template <bool AFFINE>
__device__ __forceinline__ void gemm_inplace(float* __restrict__ buf,
                                             const float* __restrict__ w,
                                             const float* __restrict__ bias,
                                             const float* __restrict__ sc,
                                             const float* __restrict__ sh, int t) {
    for (int u = t; u < ROI * 2; u += 512) {
        const int r0 = (u >> 2) * 2;
        const int cq = u & 3;
        float acc0[8], acc1[8];
#pragma unroll
        for (int c = 0; c < 8; c++) {
            float b = AFFINE ? bias[cq * 8 + c] : 0.f;
            acc0[c] = b;
            acc1[c] = b;
        }
        const float* row0 = &buf[r0 * SA];
        const float* row1 = row0 + SA;
#pragma unroll
        for (int k = 0; k < CH; k += 2) {
            float2 a0 = *(const float2*)&row0[k];
            float2 a1 = *(const float2*)&row1[k];
            const float* wr0 = &w[k * CH + cq * 8];
            const float* wr1 = wr0 + CH;
            float4 wa = *(const float4*)wr0;
            float4 wb = *(const float4*)(wr0 + 4);
            float4 wc = *(const float4*)wr1;
            float4 wd = *(const float4*)(wr1 + 4);
            float wv0[8] = {wa.x, wa.y, wa.z, wa.w, wb.x, wb.y, wb.z, wb.w};
            float wv1[8] = {wc.x, wc.y, wc.z, wc.w, wd.x, wd.y, wd.z, wd.w};
#pragma unroll
            for (int c = 0; c < 8; c++) {
                acc0[c] += a0.x * wv0[c] + a0.y * wv1[c];
                acc1[c] += a1.x * wv0[c] + a1.y * wv1[c];
            }
        }
        float* o0 = &buf[r0 * SA + cq * 8];
        float* o1 = o0 + SA;
#pragma unroll
        for (int c = 0; c < 8; c += 2) {
            float h00 = acc0[c], h01 = acc0[c + 1];
            float h10 = acc1[c], h11 = acc1[c + 1];
            if (AFFINE) {
                float s0 = sc[cq * 8 + c], t0 = sh[cq * 8 + c];
                float s1 = sc[cq * 8 + c + 1], t1 = sh[cq * 8 + c + 1];
                h00 = leakyf(h00 * s0 + t0);
                h01 = leakyf(h01 * s1 + t1);
                h10 = leakyf(h10 * s0 + t0);
                h11 = leakyf(h11 * s1 + t1);
            }
            *(float2*)&o0[c] = make_float2(h00, h01);
            *(float2*)&o1[c] = make_float2(h10, h11);
        }
    }
}

__device__ __forceinline__ void pool_partial(const float* __restrict__ h,
                                             float* __restrict__ scratch, int t) {
    const int ch = t & 31;
    const int chunk = t >> 5;   // 0..15
    float s = 0.f, m = -1e30f;
    for (int n = chunk; n < ROI; n += 16) {
        float v = h[n * SA + ch];
        s += v;
        m = fmaxf(m, v);
    }
    scratch[chunk * CH + ch] = s;
    scratch[512 + chunk * CH + ch] = m;
}

__device__ __forceinline__ void pool_final(const float* __restrict__ scratch,
                                           float* __restrict__ zg, int t) {
    if (t < CH) {
        float s = scratch[t], m = scratch[512 + t];
#pragma unroll
        for (int j = 1; j < 16; j++) {
            s += scratch[j * CH + t];
            m = fmaxf(m, scratch[512 + j * CH + t]);
        }
        zg[t] = m;
        zg[CH + t] = s / (float)ROI;
    }
}

// ---------------------------------------------------------------------------
// K3: fused both GIN layers + both poolings. One block (512 thr) per graph.
// LDS ~77KB -> 2 blocks/CU, 16 waves/CU.
// ---------------------------------------------------------------------------
__global__ __launch_bounds__(512, 4) void k_gin(
    const float* __restrict__ y0, const int* __restrict__ packed,
    const int* __restrict__ off, const float* __restrict__ eps0p,
    const float* __restrict__ b1_0, const float* __restrict__ W2_0,
    const float* __restrict__ b2_0, const float* __restrict__ bn0_g,
    const float* __restrict__ bn0_b, const float* __restrict__ bn0_m,
    const float* __restrict__ bn0_v, const float* __restrict__ eps1p,
    const float* __restrict__ W1_1, const float* __restrict__ b1_1,
    const float* __restrict__ W2_1, const float* __restrict__ b2_1,
    const float* __restrict__ bn1_g, const float* __restrict__ bn1_b,
    const float* __restrict__ bn1_m, const float* __restrict__ bn1_v,
    float* __restrict__ z) {
    __shared__ float bufA[ROI * SA];   // 36448 B
    __shared__ float bufB[ROI * SB];   // 35376 B (also pool scratch)
    __shared__ float w[CH * CH];       // 4096 B
    __shared__ float prm[8 * CH];      // 1024 B
    __shared__ float epss[2];

    const int t = threadIdx.x;
    const int g = blockIdx.x;

    if (t < CH) {
        prm[0 * CH + t] = b1_0[t];
        prm[1 * CH + t] = b2_0[t];
        float s0 = bn0_g[t] * rsqrtf(bn0_v[t] + BN_EPS);
        prm[2 * CH + t] = s0;
        prm[3 * CH + t] = bn0_b[t] - bn0_m[t] * s0;
        prm[4 * CH + t] = b1_1[t];
        prm[5 * CH + t] = b2_1[t];
        float s1 = bn1_g[t] * rsqrtf(bn1_v[t] + BN_EPS);
        prm[6 * CH + t] = s1;
        prm[7 * CH + t] = bn1_b[t] - bn1_m[t] * s1;
    }
    if (t == 0) {
        epss[0] = 1.0f + *eps0p;
        epss[1] = 1.0f + *eps1p;
    }

    // stage y0 -> bufA (stride SA), zero bufB, load W2_0
    const float* yg = y0 + (size_t)g * ROI * CH;
    for (int f = t; f < (ROI * CH) / 4; f += 512) {
        float4 v = ((const float4*)yg)[f];
        int row = f >> 3, c4 = (f & 7) << 2;
        float* p = &bufA[row * SA + c4];
        *(float2*)p = make_float2(v.x, v.y);
        *(float2*)(p + 2) = make_float2(v.z, v.w);
    }
    for (int i = t; i < ROI * SB; i += 512) bufB[i] = 0.f;
    for (int i = t; i < (CH * CH) / 4; i += 512)
        ((float4*)w)[i] = ((const float4*)W2_0)[i];
    __syncthreads();

    const int base = off[g];
    const int nE = off[g + 1] - base;

    // layer-0 aggregation (fire-and-forget ds_add_f32)
    edge_agg(bufA, bufB, packed + base, nE, t);
    __syncthreads();

    // A0 = leaky((1+eps0)*y + agg + b1_0), in place in bufA
    {
        float e0 = epss[0];
        for (int i = t; i < ROI * CH; i += 512) {
            int n = i >> 5, c = i & 31;
            float v = e0 * bufA[n * SA + c] + bufB[n * SB + c] + prm[c];
            bufA[n * SA + c] = leakyf(v);
        }
    }
    __syncthreads();

    // h0 = leaky(bn(A0 @ W2_0 + b2_0)), in place
    gemm_inplace<true>(bufA, w, &prm[1 * CH], &prm[2 * CH], &prm[3 * CH], t);
    __syncthreads();

    // pool0 partials into bufB scratch; reload w <- W1_1 (w readers are done)
    pool_partial(bufA, bufB, t);
    for (int i = t; i < (CH * CH) / 4; i += 512)
        ((float4*)w)[i] = ((const float4*)W1_1)[i];
    __syncthreads();

    pool_final(bufB, z + (size_t)g * 128, t);
    // y1 = h0 @ W1_1 in place (doesn't touch bufB scratch)
    gemm_inplace<false>(bufA, w, nullptr, nullptr, nullptr, t);
    __syncthreads();

    for (int i = t; i < ROI * SB; i += 512) bufB[i] = 0.f;
    __syncthreads();

    // layer-1 aggregation
    edge_agg(bufA, bufB, packed + base, nE, t);
    __syncthreads();

    // A1 = leaky((1+eps1)*y1 + agg1 + b1_1) in place; reload w <- W2_1
    {
        float e1 = epss[1];
        for (int i = t; i < ROI * CH; i += 512) {
            int n = i >> 5, c = i & 31;
            float v = e1 * bufA[n * SA + c] + bufB[n * SB + c] + prm[4 * CH + c];
            bufA[n * SA + c] = leakyf(v);
        }
    }
    for (int i = t; i < (CH * CH) / 4; i += 512)
        ((float4*)w)[i] = ((const float4*)W2_1)[i];
    __syncthreads();

    gemm_inplace<true>(bufA, w, &prm[5 * CH], &prm[6 * CH], &prm[7 * CH], t);
    __syncthreads();

    pool_partial(bufA, bufB, t);
    __syncthreads();
    pool_final(bufB, z + (size_t)g * 128 + 64, t);
}

// ---------------------------------------------------------------------------
// K4: head MLP  z[512,128] -> 256 -> 128 -> 1
// ---------------------------------------------------------------------------
__global__ __launch_bounds__(256) void k_head(
    const float* __restrict__ z, const float* __restrict__ W1,
    const float* __restrict__ b1, const float* __restrict__ g1,
    const float* __restrict__ be1, const float* __restrict__ m1,
    const float* __restrict__ v1, const float* __restrict__ W2,
    const float* __restrict__ b2, const float* __restrict__ g2,
    const float* __restrict__ be2, const float* __restrict__ m2,
    const float* __restrict__ v2, const float* __restrict__ W3,
    const float* __restrict__ b3, float* __restrict__ out) {
    __shared__ float zr[128], z1[256], z2[128];
    const int t = threadIdx.x;
    const int g = blockIdx.x;

    if (t < 32) ((float4*)zr)[t] = ((const float4*)(z + (size_t)g * 128))[t];
    __syncthreads();
    {
        float acc = b1[t];
#pragma unroll 8
        for (int k = 0; k < 128; k++) acc += zr[k] * W1[k * 256 + t];
        float s = g1[t] * rsqrtf(v1[t] + BN_EPS);
        acc = (acc - m1[t]) * s + be1[t];
        z1[t] = leakyf(acc);
    }
    __syncthreads();
    if (t < 128) {
        float acc = b2[t];
#pragma unroll 8
        for (int k = 0; k < 256; k++) acc += z1[k] * W2[k * 128 + t];
        float s = g2[t] * rsqrtf(v2[t] + BN_EPS);
        acc = (acc - m2[t]) * s + be2[t];
        z2[t] = leakyf(acc);
    }
    __syncthreads();
    if (t < 64) {
        float v = z2[t] * W3[t] + z2[t + 64] * W3[t + 64];
        for (int offd = 32; offd; offd >>= 1) v += __shfl_down(v, offd);
        if (t == 0) out[g] = v + b3[0];
    }
}

// ---------------------------------------------------------------------------
extern "C" void kernel_launch(void* const* d_in, const int* in_sizes, int n_in,
                              void* d_out, int out_size, void* d_ws, size_t ws_size,
                              hipStream_t stream) {
    const float* x      = (const float*)d_in[0];
    const int* eidx     = (const int*)d_in[1];
    const float* eps0   = (const float*)d_in[3];
    const float* W1_0   = (const float*)d_in[4];
    const float* b1_0   = (const float*)d_in[5];
    const float* W2_0   = (const float*)d_in[6];
    const float* b2_0   = (const float*)d_in[7];
    const float* bn0_g  = (const float*)d_in[8];
    const float* bn0_b  = (const float*)d_in[9];
    const float* bn0_m  = (const float*)d_in[10];
    const float* bn0_v  = (const float*)d_in[11];
    const float* eps1   = (const float*)d_in[12];
    const float* W1_1   = (const float*)d_in[13];
    const float* b1_1   = (const float*)d_in[14];
    const float* W2_1   = (const float*)d_in[15];
    const float* b2_1   = (const float*)d_in[16];
    const float* bn1_g  = (const float*)d_in[17];
    const float* bn1_b  = (const float*)d_in[18];
    const float* bn1_m  = (const float*)d_in[19];
    const float* bn1_v  = (const float*)d_in[20];
    const float* lin1_W = (const float*)d_in[21];
    const float* lin1_b = (const float*)d_in[22];
    const float* hbn1_g = (const float*)d_in[23];
    const float* hbn1_b = (const float*)d_in[24];
    const float* hbn1_m = (const float*)d_in[25];
    const float* hbn1_v = (const float*)d_in[26];
    const float* lin2_W = (const float*)d_in[27];
    const float* lin2_b = (const float*)d_in[28];
    const float* hbn2_g = (const float*)d_in[29];
    const float* hbn2_b = (const float*)d_in[30];
    const float* hbn2_m = (const float*)d_in[31];
    const float* hbn2_v = (const float*)d_in[32];
    const float* lin3_W = (const float*)d_in[33];
    const float* lin3_b = (const float*)d_in[34];

    const int E = in_sizes[1] / 2;
    const int* src = eidx;
    const int* dst = eidx + E;

    char* ws = (char*)d_ws;
    const size_t Y0_OFF  = 0;
    const size_t Z_OFF   = (size_t)NNODES * CH * 4;        // 17,563,648
    const size_t CNT_OFF = Z_OFF + (size_t)NG * 128 * 4;
    const size_t CUR_OFF = CNT_OFF + 2048;
    const size_t OFF_OFF = CUR_OFF + NG * 16 * 4;          // padded counters
    const size_t PKD_OFF = OFF_OFF + 2304;

    float* y0    = (float*)(ws + Y0_OFF);
    float* z     = (float*)(ws + Z_OFF);
    int* cnt     = (int*)(ws + CNT_OFF);
    int* cur     = (int*)(ws + CUR_OFF);
    int* off     = (int*)(ws + OFF_OFF);
    int* packed  = (int*)(ws + PKD_OFF);

    k_gemm1<<<NNODES / 256, 256, 0, stream>>>(x, W1_0, y0);

    hipMemsetAsync(cnt, 0, NG * sizeof(int), stream);
    k_hist<<<256, 256, 0, stream>>>(dst, E, cnt);
    k_scan<<<1, NG, 0, stream>>>(cnt, off, cur);
    k_scatter<<<512, 256, 0, stream>>>(src, dst, E, cur, packed);

    k_gin<<<NG, 512, 0, stream>>>(y0, packed, off, eps0, b1_0, W2_0, b2_0,
                                  bn0_g, bn0_b, bn0_m, bn0_v, eps1, W1_1, b1_1,
                                  W2_1, b2_1, bn1_g, bn1_b, bn1_m, bn1_v, z);

    k_head<<<NG, 256, 0, stream>>>(z, lin1_W, lin1_b, hbn1_g, hbn1_b, hbn1_m,
                                   hbn1_v, lin2_W, lin2_b, hbn2_g, hbn2_b,
                                   hbn2_m, hbn2_v, lin3_W, lin3_b,
                                   (float*)d_out);
}

// Round 3
// 971.155 us; speedup vs baseline: 1.1381x; 1.1381x over previous
//
#include <hip/hip_runtime.h>

#define ROI 268
#define NG 512
#define NNODES (NG * ROI)   // 137216
#define CH 32
#define SLOPE 0.33f
#define BN_EPS 1e-5f
#define SA 34               // bufA row stride (words): even -> b64-aligned rows
#define SB 33               // bufB row stride (words)

__device__ __forceinline__ float leakyf(float v) {
    return v > 0.f ? v : SLOPE * v;
}

// native ds_add_f32 (no CAS loop, no return value -> fire-and-forget)
__device__ __forceinline__ void lds_fadd(float* p, float v) {
    __hip_atomic_fetch_add(p, v, __ATOMIC_RELAXED, __HIP_MEMORY_SCOPE_WORKGROUP);
}

// ---------------------------------------------------------------------------
// K1: y0[N,32] = x[N,268] @ W1_0[268,32]   (fp32 vector GEMM)
// ---------------------------------------------------------------------------
__global__ __launch_bounds__(256, 2) void k_gemm1(
    const float* __restrict__ x, const float* __restrict__ W1,
    float* __restrict__ y0) {
    __shared__ float sW[ROI * CH];
    __shared__ float sA[32 * 261];   // stride 261 (mod 32 = 5): conflict-free stores

    const int tid = threadIdx.x;
    const size_t rowbase = (size_t)blockIdx.x * 256;

    for (int i = tid; i < (ROI * CH) / 4; i += 256)
        ((float4*)sW)[i] = ((const float4*)W1)[i];

    float acc[4][8];
#pragma unroll
    for (int r = 0; r < 4; r++)
#pragma unroll
        for (int c = 0; c < 8; c++) acc[r][c] = 0.f;

    const int rg = tid >> 2;
    const int cg = tid & 3;

    int k0 = 0;
    for (int chunk = 0; chunk < 9; ++chunk) {
        const int ksize = (chunk < 8) ? 32 : 12;
        __syncthreads();
        const int nf4 = (ksize >> 2) << 8;
        for (int f = tid; f < nf4; f += 256) {
            int row, kk;
            if (ksize == 32) { row = f >> 3; kk = (f & 7) << 2; }
            else             { row = f & 255; kk = (f >> 8) << 2; }
            float4 v = *(const float4*)&x[(rowbase + row) * ROI + k0 + kk];
            sA[(kk + 0) * 261 + row] = v.x;
            sA[(kk + 1) * 261 + row] = v.y;
            sA[(kk + 2) * 261 + row] = v.z;
            sA[(kk + 3) * 261 + row] = v.w;
        }
        __syncthreads();
#pragma unroll 4
        for (int kk = 0; kk < ksize; ++kk) {
            float4 a4 = *(float4*)&sA[kk * 261 + rg * 4];
            const float* wr = &sW[(k0 + kk) * CH + cg * 8];
            float4 w0 = *(const float4*)wr;
            float4 w1 = *(const float4*)(wr + 4);
            float av[4] = {a4.x, a4.y, a4.z, a4.w};
            float wv[8] = {w0.x, w0.y, w0.z, w0.w, w1.x, w1.y, w1.z, w1.w};
#pragma unroll
            for (int r = 0; r < 4; r++)
#pragma unroll
                for (int c = 0; c < 8; c++) acc[r][c] += av[r] * wv[c];
        }
        k0 += ksize;
    }

#pragma unroll
    for (int r = 0; r < 4; r++) {
        size_t row = rowbase + rg * 4 + r;
        *(float4*)&y0[row * CH + cg * 8] =
            make_float4(acc[r][0], acc[r][1], acc[r][2], acc[r][3]);
        *(float4*)&y0[row * CH + cg * 8 + 4] =
            make_float4(acc[r][4], acc[r][5], acc[r][6], acc[r][7]);
    }
}

// ---------------------------------------------------------------------------
// K2: bucket edges by graph
// ---------------------------------------------------------------------------
__global__ void k_hist(const int* __restrict__ dst, int E, int* __restrict__ cnt) {
    __shared__ int h[NG];
    for (int i = threadIdx.x; i < NG; i += blockDim.x) h[i] = 0;
    __syncthreads();
    int stride = gridDim.x * blockDim.x;
    for (int i = blockIdx.x * blockDim.x + threadIdx.x; i < E; i += stride)
        atomicAdd(&h[dst[i] / ROI], 1);
    __syncthreads();
    for (int i = threadIdx.x; i < NG; i += blockDim.x)
        if (h[i]) atomicAdd(&cnt[i], h[i]);
}

__global__ void k_scan(const int* __restrict__ cnt, int* __restrict__ off,
                       int* __restrict__ cur) {
    __shared__ int s[NG];
    int t = threadIdx.x;   // 512 threads
    int myc = cnt[t];
    s[t] = myc;
    __syncthreads();
    for (int d = 1; d < NG; d <<= 1) {
        int v = (t >= d) ? s[t - d] : 0;
        __syncthreads();
        s[t] += v;
        __syncthreads();
    }
    int inc = s[t];
    int exc = inc - myc;
    off[t] = exc;
    cur[t * 16] = exc;              // padded: one counter per 64B line
    if (t == NG - 1) off[NG] = inc;
}

__global__ void k_scatter(const int* __restrict__ src, const int* __restrict__ dst,
                          int E, int* __restrict__ cur, int* __restrict__ packed) {
    int stride = gridDim.x * blockDim.x;
    for (int i = blockIdx.x * blockDim.x + threadIdx.x; i < E; i += stride) {
        int d = dst[i];
        int g = d / ROI;
        int s_ = src[i];
        int pos = atomicAdd(&cur[g * 16], 1);
        // pre-multiplied LDS word offsets: low16 = srcLocal*SA, high16 = dstLocal*SB
        packed[pos] = ((s_ - g * ROI) * SA) | (((d - g * ROI) * SB) << 16);
    }
}

// ---------------------------------------------------------------------------
// K3 helpers
// ---------------------------------------------------------------------------
__device__ __forceinline__ void edge_agg(const float* __restrict__ bufA,
                                         float* __restrict__ bufB,
                                         const int* __restrict__ ep, int nE,
                                         int t) {
    const int ch = t & 31;
    const int slot = t >> 5;   // 0..15
    int i = slot;
    for (; i + 48 < nE; i += 64) {
        int p0 = ep[i], p1 = ep[i + 16], p2 = ep[i + 32], p3 = ep[i + 48];
        float v0 = bufA[(p0 & 0xffff) + ch];
        float v1 = bufA[(p1 & 0xffff) + ch];
        float v2 = bufA[(p2 & 0xffff) + ch];
        float v3 = bufA[(p3 & 0xffff) + ch];
        lds_fadd(&bufB[(p0 >> 16) + ch], v0);
        lds_fadd(&bufB[(p1 >> 16) + ch], v1);
        lds_fadd(&bufB[(p2 >> 16) + ch], v2);
        lds_fadd(&bufB[(p3 >> 16) + ch], v3);
    }
    for (; i < nE; i += 16) {
        int p = ep[i];
        lds_fadd(&bufB[(p >> 16) + ch], bufA[(p & 0xffff) + ch]);
    }
}

// in-place row-local GEMM: buf[268 rows, stride SA] <- act(buf @ w)
// unit = row-pair (134) x col-quarter (4) = 536 units over 512 threads.
template <bool AFFINE>
__device__ __forceinline__ void gemm_inplace(float* __restrict__ buf,
                                             const float* __restrict__ w,
                                             const float* __restrict__ bias,
                                             const float* __restrict__ sc,
                                             const float* __restrict__ sh, int t) {
    for (int u = t; u < ROI * 2; u += 512) {
        const int r0 = (u >> 2) * 2;
        const int cq = u & 3;
        float acc0[8], acc1[8];
#pragma unroll
        for (int c = 0; c < 8; c++) {
            float b = AFFINE ? bias[cq * 8 + c] : 0.f;
            acc0[c] = b;
            acc1[c] = b;
        }
        const float* row0 = &buf[r0 * SA];
        const float* row1 = row0 + SA;
#pragma unroll
        for (int k = 0; k < CH; k += 2) {
            float2 a0 = *(const float2*)&row0[k];
            float2 a1 = *(const float2*)&row1[k];
            const float* wr0 = &w[k * CH + cq * 8];
            const float* wr1 = wr0 + CH;
            float4 wa = *(const float4*)wr0;
            float4 wb = *(const float4*)(wr0 + 4);
            float4 wc = *(const float4*)wr1;
            float4 wd = *(const float4*)(wr1 + 4);
            acc0[0] += a0.x * wa.x + a0.y * wc.x;
            acc0[1] += a0.x * wa.y + a0.y * wc.y;
            acc0[2] += a0.x * wa.z + a0.y * wc.z;
            acc0[3] += a0.x * wa.w + a0.y * wc.w;
            acc0[4] += a0.x * wb.x + a0.y * wd.x;
            acc0[5] += a0.x * wb.y + a0.y * wd.y;
            acc0[6] += a0.x * wb.z + a0.y * wd.z;
            acc0[7] += a0.x * wb.w + a0.y * wd.w;
            acc1[0] += a1.x * wa.x + a1.y * wc.x;
            acc1[1] += a1.x * wa.y + a1.y * wc.y;
            acc1[2] += a1.x * wa.z + a1.y * wc.z;
            acc1[3] += a1.x * wa.w + a1.y * wc.w;
            acc1[4] += a1.x * wb.x + a1.y * wd.x;
            acc1[5] += a1.x * wb.y + a1.y * wd.y;
            acc1[6] += a1.x * wb.z + a1.y * wd.z;
            acc1[7] += a1.x * wb.w + a1.y * wd.w;
        }
        float* o0 = &buf[r0 * SA + cq * 8];
        float* o1 = o0 + SA;
#pragma unroll
        for (int c = 0; c < 8; c += 2) {
            float h00 = acc0[c], h01 = acc0[c + 1];
            float h10 = acc1[c], h11 = acc1[c + 1];
            if (AFFINE) {
                float s0 = sc[cq * 8 + c], t0 = sh[cq * 8 + c];
                float s1 = sc[cq * 8 + c + 1], t1 = sh[cq * 8 + c + 1];
                h00 = leakyf(h00 * s0 + t0);
                h01 = leakyf(h01 * s1 + t1);
                h10 = leakyf(h10 * s0 + t0);
                h11 = leakyf(h11 * s1 + t1);
            }
            *(float2*)&o0[c] = make_float2(h00, h01);
            *(float2*)&o1[c] = make_float2(h10, h11);
        }
    }
}

__device__ __forceinline__ void pool_partial(const float* __restrict__ h,
                                             float* __restrict__ scratch, int t) {
    const int ch = t & 31;
    const int chunk = t >> 5;   // 0..15
    float s = 0.f, m = -1e30f;
    for (int n = chunk; n < ROI; n += 16) {
        float v = h[n * SA + ch];
        s += v;
        m = fmaxf(m, v);
    }
    scratch[chunk * CH + ch] = s;
    scratch[512 + chunk * CH + ch] = m;
}

__device__ __forceinline__ void pool_final(const float* __restrict__ scratch,
                                           float* __restrict__ zg, int t) {
    if (t < CH) {
        float s = scratch[t], m = scratch[512 + t];
#pragma unroll
        for (int j = 1; j < 16; j++) {
            s += scratch[j * CH + t];
            m = fmaxf(m, scratch[512 + j * CH + t]);
        }
        zg[t] = m;
        zg[CH + t] = s / (float)ROI;
    }
}

// ---------------------------------------------------------------------------
// K3: fused both GIN layers + both poolings. One block (512 thr) per graph.
// LDS ~77KB -> 2 blocks/CU. launch_bounds(512,2): VGPR cap 128 (NOT 4 -> 64,
// which forced scratch spill = 1.6 GB HBM traffic in round 2).
// ---------------------------------------------------------------------------
__global__ __launch_bounds__(512, 2) void k_gin(
    const float* __restrict__ y0, const int* __restrict__ packed,
    const int* __restrict__ off, const float* __restrict__ eps0p,
    const float* __restrict__ b1_0, const float* __restrict__ W2_0,
    const float* __restrict__ b2_0, const float* __restrict__ bn0_g,
    const float* __restrict__ bn0_b, const float* __restrict__ bn0_m,
    const float* __restrict__ bn0_v, const float* __restrict__ eps1p,
    const float* __restrict__ W1_1, const float* __restrict__ b1_1,
    const float* __restrict__ W2_1, const float* __restrict__ b2_1,
    const float* __restrict__ bn1_g, const float* __restrict__ bn1_b,
    const float* __restrict__ bn1_m, const float* __restrict__ bn1_v,
    float* __restrict__ z) {
    __shared__ float bufA[ROI * SA];   // 36448 B
    __shared__ float bufB[ROI * SB];   // 35376 B (also pool scratch)
    __shared__ float w[CH * CH];       // 4096 B
    __shared__ float prm[8 * CH];      // 1024 B
    __shared__ float epss[2];

    const int t = threadIdx.x;
    const int g = blockIdx.x;

    if (t < CH) {
        prm[0 * CH + t] = b1_0[t];
        prm[1 * CH + t] = b2_0[t];
        float s0 = bn0_g[t] * rsqrtf(bn0_v[t] + BN_EPS);
        prm[2 * CH + t] = s0;
        prm[3 * CH + t] = bn0_b[t] - bn0_m[t] * s0;
        prm[4 * CH + t] = b1_1[t];
        prm[5 * CH + t] = b2_1[t];
        float s1 = bn1_g[t] * rsqrtf(bn1_v[t] + BN_EPS);
        prm[6 * CH + t] = s1;
        prm[7 * CH + t] = bn1_b[t] - bn1_m[t] * s1;
    }
    if (t == 0) {
        epss[0] = 1.0f + *eps0p;
        epss[1] = 1.0f + *eps1p;
    }

    // stage y0 -> bufA (stride SA), zero bufB, load W2_0
    const float* yg = y0 + (size_t)g * ROI * CH;
    for (int f = t; f < (ROI * CH) / 4; f += 512) {
        float4 v = ((const float4*)yg)[f];
        int row = f >> 3, c4 = (f & 7) << 2;
        float* p = &bufA[row * SA + c4];
        *(float2*)p = make_float2(v.x, v.y);
        *(float2*)(p + 2) = make_float2(v.z, v.w);
    }
    for (int i = t; i < ROI * SB; i += 512) bufB[i] = 0.f;
    for (int i = t; i < (CH * CH) / 4; i += 512)
        ((float4*)w)[i] = ((const float4*)W2_0)[i];
    __syncthreads();

    const int base = off[g];
    const int nE = off[g + 1] - base;

    // layer-0 aggregation (fire-and-forget ds_add_f32)
    edge_agg(bufA, bufB, packed + base, nE, t);
    __syncthreads();

    // A0 = leaky((1+eps0)*y + agg + b1_0), in place in bufA
    {
        float e0 = epss[0];
        for (int i = t; i < ROI * CH; i += 512) {
            int n = i >> 5, c = i & 31;
            float v = e0 * bufA[n * SA + c] + bufB[n * SB + c] + prm[c];
            bufA[n * SA + c] = leakyf(v);
        }
    }
    __syncthreads();

    // h0 = leaky(bn(A0 @ W2_0 + b2_0)), in place
    gemm_inplace<true>(bufA, w, &prm[1 * CH], &prm[2 * CH], &prm[3 * CH], t);
    __syncthreads();

    // pool0 partials into bufB scratch; reload w <- W1_1 (w readers are done)
    pool_partial(bufA, bufB, t);
    for (int i = t; i < (CH * CH) / 4; i += 512)
        ((float4*)w)[i] = ((const float4*)W1_1)[i];
    __syncthreads();

    pool_final(bufB, z + (size_t)g * 128, t);
    // y1 = h0 @ W1_1 in place (doesn't touch bufB scratch)
    gemm_inplace<false>(bufA, w, nullptr, nullptr, nullptr, t);
    __syncthreads();

    for (int i = t; i < ROI * SB; i += 512) bufB[i] = 0.f;
    __syncthreads();

    // layer-1 aggregation
    edge_agg(bufA, bufB, packed + base, nE, t);
    __syncthreads();

    // A1 = leaky((1+eps1)*y1 + agg1 + b1_1) in place; reload w <- W2_1
    {
        float e1 = epss[1];
        for (int i = t; i < ROI * CH; i += 512) {
            int n = i >> 5, c = i & 31;
            float v = e1 * bufA[n * SA + c] + bufB[n * SB + c] + prm[4 * CH + c];
            bufA[n * SA + c] = leakyf(v);
        }
    }
    for (int i = t; i < (CH * CH) / 4; i += 512)
        ((float4*)w)[i] = ((const float4*)W2_1)[i];
    __syncthreads();

    gemm_inplace<true>(bufA, w, &prm[5 * CH], &prm[6 * CH], &prm[7 * CH], t);
    __syncthreads();

    pool_partial(bufA, bufB, t);
    __syncthreads();
    pool_final(bufB, z + (size_t)g * 128 + 64, t);
}

// ---------------------------------------------------------------------------
// K4: head MLP  z[512,128] -> 256 -> 128 -> 1
// ---------------------------------------------------------------------------
__global__ __launch_bounds__(256) void k_head(
    const float* __restrict__ z, const float* __restrict__ W1,
    const float* __restrict__ b1, const float* __restrict__ g1,
    const float* __restrict__ be1, const float* __restrict__ m1,
    const float* __restrict__ v1, const float* __restrict__ W2,
    const float* __restrict__ b2, const float* __restrict__ g2,
    const float* __restrict__ be2, const float* __restrict__ m2,
    const float* __restrict__ v2, const float* __restrict__ W3,
    const float* __restrict__ b3, float* __restrict__ out) {
    __shared__ float zr[128], z1[256], z2[128];
    const int t = threadIdx.x;
    const int g = blockIdx.x;

    if (t < 32) ((float4*)zr)[t] = ((const float4*)(z + (size_t)g * 128))[t];
    __syncthreads();
    {
        float acc = b1[t];
#pragma unroll 8
        for (int k = 0; k < 128; k++) acc += zr[k] * W1[k * 256 + t];
        float s = g1[t] * rsqrtf(v1[t] + BN_EPS);
        acc = (acc - m1[t]) * s + be1[t];
        z1[t] = leakyf(acc);
    }
    __syncthreads();
    if (t < 128) {
        float acc = b2[t];
#pragma unroll 8
        for (int k = 0; k < 256; k++) acc += z1[k] * W2[k * 128 + t];
        float s = g2[t] * rsqrtf(v2[t] + BN_EPS);
        acc = (acc - m2[t]) * s + be2[t];
        z2[t] = leakyf(acc);
    }
    __syncthreads();
    if (t < 64) {
        float v = z2[t] * W3[t] + z2[t + 64] * W3[t + 64];
        for (int offd = 32; offd; offd >>= 1) v += __shfl_down(v, offd);
        if (t == 0) out[g] = v + b3[0];
    }
}

// ---------------------------------------------------------------------------
extern "C" void kernel_launch(void* const* d_in, const int* in_sizes, int n_in,
                              void* d_out, int out_size, void* d_ws, size_t ws_size,
                              hipStream_t stream) {
    const float* x      = (const float*)d_in[0];
    const int* eidx     = (const int*)d_in[1];
    const float* eps0   = (const float*)d_in[3];
    const float* W1_0   = (const float*)d_in[4];
    const float* b1_0   = (const float*)d_in[5];
    const float* W2_0   = (const float*)d_in[6];
    const float* b2_0   = (const float*)d_in[7];
    const float* bn0_g  = (const float*)d_in[8];
    const float* bn0_b  = (const float*)d_in[9];
    const float* bn0_m  = (const float*)d_in[10];
    const float* bn0_v  = (const float*)d_in[11];
    const float* eps1   = (const float*)d_in[12];
    const float* W1_1   = (const float*)d_in[13];
    const float* b1_1   = (const float*)d_in[14];
    const float* W2_1   = (const float*)d_in[15];
    const float* b2_1   = (const float*)d_in[16];
    const float* bn1_g  = (const float*)d_in[17];
    const float* bn1_b  = (const float*)d_in[18];
    const float* bn1_m  = (const float*)d_in[19];
    const float* bn1_v  = (const float*)d_in[20];
    const float* lin1_W = (const float*)d_in[21];
    const float* lin1_b = (const float*)d_in[22];
    const float* hbn1_g = (const float*)d_in[23];
    const float* hbn1_b = (const float*)d_in[24];
    const float* hbn1_m = (const float*)d_in[25];
    const float* hbn1_v = (const float*)d_in[26];
    const float* lin2_W = (const float*)d_in[27];
    const float* lin2_b = (const float*)d_in[28];
    const float* hbn2_g = (const float*)d_in[29];
    const float* hbn2_b = (const float*)d_in[30];
    const float* hbn2_m = (const float*)d_in[31];
    const float* hbn2_v = (const float*)d_in[32];
    const float* lin3_W = (const float*)d_in[33];
    const float* lin3_b = (const float*)d_in[34];

    const int E = in_sizes[1] / 2;
    const int* src = eidx;
    const int* dst = eidx + E;

    char* ws = (char*)d_ws;
    const size_t Y0_OFF  = 0;
    const size_t Z_OFF   = (size_t)NNODES * CH * 4;        // 17,563,648
    const size_t CNT_OFF = Z_OFF + (size_t)NG * 128 * 4;
    const size_t CUR_OFF = CNT_OFF + 2048;
    const size_t OFF_OFF = CUR_OFF + NG * 16 * 4;          // padded counters
    const size_t PKD_OFF = OFF_OFF + 2304;

    float* y0    = (float*)(ws + Y0_OFF);
    float* z     = (float*)(ws + Z_OFF);
    int* cnt     = (int*)(ws + CNT_OFF);
    int* cur     = (int*)(ws + CUR_OFF);
    int* off     = (int*)(ws + OFF_OFF);
    int* packed  = (int*)(ws + PKD_OFF);

    k_gemm1<<<NNODES / 256, 256, 0, stream>>>(x, W1_0, y0);

    hipMemsetAsync(cnt, 0, NG * sizeof(int), stream);
    k_hist<<<256, 256, 0, stream>>>(dst, E, cnt);
    k_scan<<<1, NG, 0, stream>>>(cnt, off, cur);
    k_scatter<<<512, 256, 0, stream>>>(src, dst, E, cur, packed);

    k_gin<<<NG, 512, 0, stream>>>(y0, packed, off, eps0, b1_0, W2_0, b2_0,
                                  bn0_g, bn0_b, bn0_m, bn0_v, eps1, W1_1, b1_1,
                                  W2_1, b2_1, bn1_g, bn1_b, bn1_m, bn1_v, z);

    k_head<<<NG, 256, 0, stream>>>(z, lin1_W, lin1_b, hbn1_g, hbn1_b, hbn1_m,
                                   hbn1_v, lin2_W, lin2_b, hbn2_g, hbn2_b,
                                   hbn2_m, hbn2_v, lin3_W, lin3_b,
                                   (float*)d_out);
}

// Round 4
// 580.412 us; speedup vs baseline: 1.9043x; 1.6732x over previous
//
#include <hip/hip_runtime.h>

#define ROI 268
#define NG 512
#define NNODES (NG * ROI)   // 137216
#define CH 32
#define SLOPE 0.33f
#define BN_EPS 1e-5f
#define SR 34               // LDS row stride (words), even -> 8B-aligned rows

__device__ __forceinline__ float leakyf(float v) {
    return v > 0.f ? v : SLOPE * v;
}

// ---------------------------------------------------------------------------
// K1: y0[N,32] = x[N,268] @ W1_0[268,32]   (fp32 vector GEMM)
// ---------------------------------------------------------------------------
__global__ __launch_bounds__(256, 2) void k_gemm1(
    const float* __restrict__ x, const float* __restrict__ W1,
    float* __restrict__ y0) {
    __shared__ float sW[ROI * CH];
    __shared__ float sA[32 * 261];

    const int tid = threadIdx.x;
    const size_t rowbase = (size_t)blockIdx.x * 256;

    for (int i = tid; i < (ROI * CH) / 4; i += 256)
        ((float4*)sW)[i] = ((const float4*)W1)[i];

    float acc[4][8];
#pragma unroll
    for (int r = 0; r < 4; r++)
#pragma unroll
        for (int c = 0; c < 8; c++) acc[r][c] = 0.f;

    const int rg = tid >> 2;
    const int cg = tid & 3;

    int k0 = 0;
    for (int chunk = 0; chunk < 9; ++chunk) {
        const int ksize = (chunk < 8) ? 32 : 12;
        __syncthreads();
        const int nf4 = (ksize >> 2) << 8;
        for (int f = tid; f < nf4; f += 256) {
            int row, kk;
            if (ksize == 32) { row = f >> 3; kk = (f & 7) << 2; }
            else             { row = f & 255; kk = (f >> 8) << 2; }
            float4 v = *(const float4*)&x[(rowbase + row) * ROI + k0 + kk];
            sA[(kk + 0) * 261 + row] = v.x;
            sA[(kk + 1) * 261 + row] = v.y;
            sA[(kk + 2) * 261 + row] = v.z;
            sA[(kk + 3) * 261 + row] = v.w;
        }
        __syncthreads();
#pragma unroll 4
        for (int kk = 0; kk < ksize; ++kk) {
            float4 a4 = *(float4*)&sA[kk * 261 + rg * 4];
            const float* wr = &sW[(k0 + kk) * CH + cg * 8];
            float4 w0 = *(const float4*)wr;
            float4 w1 = *(const float4*)(wr + 4);
            float av[4] = {a4.x, a4.y, a4.z, a4.w};
            float wv[8] = {w0.x, w0.y, w0.z, w0.w, w1.x, w1.y, w1.z, w1.w};
#pragma unroll
            for (int r = 0; r < 4; r++)
#pragma unroll
                for (int c = 0; c < 8; c++) acc[r][c] += av[r] * wv[c];
        }
        k0 += ksize;
    }

#pragma unroll
    for (int r = 0; r < 4; r++) {
        size_t row = rowbase + rg * 4 + r;
        *(float4*)&y0[row * CH + cg * 8] =
            make_float4(acc[r][0], acc[r][1], acc[r][2], acc[r][3]);
        *(float4*)&y0[row * CH + cg * 8 + 4] =
            make_float4(acc[r][4], acc[r][5], acc[r][6], acc[r][7]);
    }
}

// ---------------------------------------------------------------------------
// K2: CSR build (by dst node)
// ---------------------------------------------------------------------------
__global__ void k_hist(const int* __restrict__ dst, int E, int* __restrict__ cnt) {
    __shared__ int h[NG];
    for (int i = threadIdx.x; i < NG; i += blockDim.x) h[i] = 0;
    __syncthreads();
    int stride = gridDim.x * blockDim.x;
    for (int i = blockIdx.x * blockDim.x + threadIdx.x; i < E; i += stride)
        atomicAdd(&h[dst[i] / ROI], 1);
    __syncthreads();
    for (int i = threadIdx.x; i < NG; i += blockDim.x)
        if (h[i]) atomicAdd(&cnt[i], h[i]);
}

__global__ void k_scan(const int* __restrict__ cnt, int* __restrict__ off) {
    __shared__ int s[NG];
    int t = threadIdx.x;   // 512 threads
    int myc = cnt[t];
    s[t] = myc;
    __syncthreads();
    for (int d = 1; d < NG; d <<= 1) {
        int v = (t >= d) ? s[t - d] : 0;
        __syncthreads();
        s[t] += v;
        __syncthreads();
    }
    off[t] = s[t] - myc;
    if (t == NG - 1) off[NG] = s[t];
}

__global__ void k_deg(const int* __restrict__ dst, int E, int* __restrict__ deg) {
    int stride = gridDim.x * blockDim.x;
    for (int i = blockIdx.x * blockDim.x + threadIdx.x; i < E; i += stride)
        atomicAdd(&deg[dst[i]], 1);
}

// per-graph exclusive scan of node degrees -> row_ptr; deg becomes the fill
// cursor (safe: block only touches its own range, reads before writes)
__global__ __launch_bounds__(512) void k_scan_node(
    int* __restrict__ deg, const int* __restrict__ off,
    int* __restrict__ row_ptr) {
    __shared__ int s[512];
    const int g = blockIdx.x, t = threadIdx.x;
    int v = (t < ROI) ? deg[g * ROI + t] : 0;
    s[t] = v;
    __syncthreads();
    for (int d = 1; d < 512; d <<= 1) {
        int u = (t >= d) ? s[t - d] : 0;
        __syncthreads();
        s[t] += u;
        __syncthreads();
    }
    if (t < ROI) {
        int exc = s[t] - v + off[g];
        row_ptr[g * ROI + t] = exc;
        deg[g * ROI + t] = exc;   // reused as cursor in k_fill
    }
    if (g == NG - 1 && t == 0) row_ptr[NNODES] = off[NG];
}

__global__ void k_fill(const int* __restrict__ src, const int* __restrict__ dst,
                       int E, int* __restrict__ rcur, int* __restrict__ ebuf) {
    int stride = gridDim.x * blockDim.x;
    for (int i = blockIdx.x * blockDim.x + threadIdx.x; i < E; i += stride) {
        int d = dst[i];
        int g = d / ROI;
        int pos = atomicAdd(&rcur[d], 1);
        ebuf[pos] = (src[i] - g * ROI) * SR;   // premultiplied LDS word offset
    }
}

// ---------------------------------------------------------------------------
// K3 helpers
// ---------------------------------------------------------------------------
// out[n] = leaky(e*in[n] + sum_{j in CSR(n)} in[src_j] + b1), gather, no atomics
__device__ __forceinline__ void gather_combine(
    const float* __restrict__ in, float* __restrict__ out,
    const int* __restrict__ rp, const int* __restrict__ ebuf, float e,
    const float* __restrict__ b1, int t) {
    const int ch = t & 31;
    const int hw = t >> 5;   // 0..15
    for (int n = hw; n < ROI; n += 16) {
        int b = rp[n], en = rp[n + 1];   // uniform per half-wave (broadcast)
        float acc = 0.f;
        int j = b;
        for (; j + 3 < en; j += 4) {
            int p0 = ebuf[j], p1 = ebuf[j + 1], p2 = ebuf[j + 2], p3 = ebuf[j + 3];
            float v0 = in[p0 + ch], v1 = in[p1 + ch];
            float v2 = in[p2 + ch], v3 = in[p3 + ch];
            acc += (v0 + v1) + (v2 + v3);
        }
        for (; j < en; ++j) acc += in[ebuf[j] + ch];
        out[n * SR + ch] = leakyf(e * in[n * SR + ch] + acc + b1[ch]);
    }
}

// in-place row-local GEMM: buf[268,CH] <- act(buf @ w); out row r depends only
// on in row r -> in-place is race-free across waves.
template <bool AFFINE>
__device__ __forceinline__ void gemm_inplace(float* __restrict__ buf,
                                             const float* __restrict__ w,
                                             const float* __restrict__ bias,
                                             const float* __restrict__ sc,
                                             const float* __restrict__ sh, int t) {
    for (int u = t; u < ROI * 2; u += 512) {
        const int r0 = (u >> 2) * 2;
        const int cq = u & 3;
        float acc0[8], acc1[8];
#pragma unroll
        for (int c = 0; c < 8; c++) {
            float b = AFFINE ? bias[cq * 8 + c] : 0.f;
            acc0[c] = b;
            acc1[c] = b;
        }
        const float* row0 = &buf[r0 * SR];
        const float* row1 = row0 + SR;
        // unroll 2 ONLY: full unroll made the compiler prefetch all 64 w-float4s
        // -> >128 VGPR -> scratch spill -> 1 GB HBM traffic (rounds 2/3)
#pragma unroll 2
        for (int k = 0; k < CH; k += 2) {
            float2 a0 = *(const float2*)&row0[k];
            float2 a1 = *(const float2*)&row1[k];
            const float* wr0 = &w[k * CH + cq * 8];
            const float* wr1 = wr0 + CH;
            float4 wa = *(const float4*)wr0;
            float4 wb = *(const float4*)(wr0 + 4);
            float4 wc = *(const float4*)wr1;
            float4 wd = *(const float4*)(wr1 + 4);
            acc0[0] += a0.x * wa.x + a0.y * wc.x;
            acc0[1] += a0.x * wa.y + a0.y * wc.y;
            acc0[2] += a0.x * wa.z + a0.y * wc.z;
            acc0[3] += a0.x * wa.w + a0.y * wc.w;
            acc0[4] += a0.x * wb.x + a0.y * wd.x;
            acc0[5] += a0.x * wb.y + a0.y * wd.y;
            acc0[6] += a0.x * wb.z + a0.y * wd.z;
            acc0[7] += a0.x * wb.w + a0.y * wd.w;
            acc1[0] += a1.x * wa.x + a1.y * wc.x;
            acc1[1] += a1.x * wa.y + a1.y * wc.y;
            acc1[2] += a1.x * wa.z + a1.y * wc.z;
            acc1[3] += a1.x * wa.w + a1.y * wc.w;
            acc1[4] += a1.x * wb.x + a1.y * wd.x;
            acc1[5] += a1.x * wb.y + a1.y * wd.y;
            acc1[6] += a1.x * wb.z + a1.y * wd.z;
            acc1[7] += a1.x * wb.w + a1.y * wd.w;
        }
        float* o0 = &buf[r0 * SR + cq * 8];
        float* o1 = o0 + SR;
#pragma unroll
        for (int c = 0; c < 8; c += 2) {
            float h00 = acc0[c], h01 = acc0[c + 1];
            float h10 = acc1[c], h11 = acc1[c + 1];
            if (AFFINE) {
                float s0 = sc[cq * 8 + c], t0 = sh[cq * 8 + c];
                float s1 = sc[cq * 8 + c + 1], t1 = sh[cq * 8 + c + 1];
                h00 = leakyf(h00 * s0 + t0);
                h01 = leakyf(h01 * s1 + t1);
                h10 = leakyf(h10 * s0 + t0);
                h11 = leakyf(h11 * s1 + t1);
            }
            *(float2*)&o0[c] = make_float2(h00, h01);
            *(float2*)&o1[c] = make_float2(h10, h11);
        }
    }
}

__device__ __forceinline__ void pool_store(const float* __restrict__ h,
                                           float* __restrict__ psc, int t) {
    const int ch = t & 31;
    const int hw = t >> 5;
    const int wave = t >> 6;
    float s = 0.f, m = -1e30f;
    for (int n = hw; n < ROI; n += 16) {
        float v = h[n * SR + ch];
        s += v;
        m = fmaxf(m, v);
    }
    s += __shfl_down(s, 32);
    m = fmaxf(m, __shfl_down(m, 32));
    if ((t & 63) < 32) {
        psc[wave * 32 + ch] = s;
        psc[256 + wave * 32 + ch] = m;
    }
}

__device__ __forceinline__ void pool_final(const float* __restrict__ psc,
                                           float* __restrict__ zg, int t) {
    if (t < 32) {
        float s = 0.f, m = -1e30f;
#pragma unroll
        for (int wv = 0; wv < 8; wv++) {
            s += psc[wv * 32 + t];
            m = fmaxf(m, psc[256 + wv * 32 + t]);
        }
        zg[t] = m;
        zg[CH + t] = s / (float)ROI;
    }
}

// ---------------------------------------------------------------------------
// K3: fused both GIN layers + both poolings. One 512-thr block per graph.
// LDS 80.0 KB -> 2 blocks/CU. No atomics anywhere.
// ---------------------------------------------------------------------------
__global__ __launch_bounds__(512, 2) void k_gin(
    const float* __restrict__ y0, const int* __restrict__ row_ptr,
    const int* __restrict__ ebuf, const float* __restrict__ eps0p,
    const float* __restrict__ b1_0, const float* __restrict__ W2_0,
    const float* __restrict__ b2_0, const float* __restrict__ bn0_g,
    const float* __restrict__ bn0_b, const float* __restrict__ bn0_m,
    const float* __restrict__ bn0_v, const float* __restrict__ eps1p,
    const float* __restrict__ W1_1, const float* __restrict__ b1_1,
    const float* __restrict__ W2_1, const float* __restrict__ b2_1,
    const float* __restrict__ bn1_g, const float* __restrict__ bn1_b,
    const float* __restrict__ bn1_m, const float* __restrict__ bn1_v,
    float* __restrict__ z) {
    __shared__ float bufA[ROI * SR];   // 36448 B
    __shared__ float bufB[ROI * SR];   // 36448 B
    __shared__ float w[CH * CH];       // 4096 B
    __shared__ float prm[8 * CH];      // 1024 B
    __shared__ float psc[512];         // 2048 B pool scratch
    __shared__ float epss[2];

    const int t = threadIdx.x;
    const int g = blockIdx.x;

    if (t < CH) {
        prm[0 * CH + t] = b1_0[t];
        prm[1 * CH + t] = b2_0[t];
        float s0 = bn0_g[t] * rsqrtf(bn0_v[t] + BN_EPS);
        prm[2 * CH + t] = s0;
        prm[3 * CH + t] = bn0_b[t] - bn0_m[t] * s0;
        prm[4 * CH + t] = b1_1[t];
        prm[5 * CH + t] = b2_1[t];
        float s1 = bn1_g[t] * rsqrtf(bn1_v[t] + BN_EPS);
        prm[6 * CH + t] = s1;
        prm[7 * CH + t] = bn1_b[t] - bn1_m[t] * s1;
    }
    if (t == 0) {
        epss[0] = 1.0f + *eps0p;
        epss[1] = 1.0f + *eps1p;
    }

    // stage y0 -> bufA; load w <- W2_0
    const float* yg = y0 + (size_t)g * ROI * CH;
    for (int f = t; f < (ROI * CH) / 4; f += 512) {
        float4 v = ((const float4*)yg)[f];
        int row = f >> 3, c4 = (f & 7) << 2;
        float* p = &bufA[row * SR + c4];
        *(float2*)p = make_float2(v.x, v.y);
        *(float2*)(p + 2) = make_float2(v.z, v.w);
    }
    for (int i = t; i < (CH * CH) / 4; i += 512)
        ((float4*)w)[i] = ((const float4*)W2_0)[i];
    __syncthreads();

    const int* rp = row_ptr + g * ROI;

    // layer 0: A0 = leaky((1+eps0)*y + gather + b1_0) -> bufB
    gather_combine(bufA, bufB, rp, ebuf, epss[0], &prm[0 * CH], t);
    __syncthreads();

    // h0 = leaky(bn(A0 @ W2_0 + b2_0)), in place in bufB
    gemm_inplace<true>(bufB, w, &prm[1 * CH], &prm[2 * CH], &prm[3 * CH], t);
    __syncthreads();

    // pool0 partials; reload w <- W1_1 (previous readers done)
    pool_store(bufB, psc, t);
    for (int i = t; i < (CH * CH) / 4; i += 512)
        ((float4*)w)[i] = ((const float4*)W1_1)[i];
    __syncthreads();

    pool_final(psc, z + (size_t)g * 128, t);
    // y1 = h0 @ W1_1 in place in bufB
    gemm_inplace<false>(bufB, w, nullptr, nullptr, nullptr, t);
    __syncthreads();

    // layer 1: A1 = leaky((1+eps1)*y1 + gather + b1_1) -> bufA; reload w <- W2_1
    gather_combine(bufB, bufA, rp, ebuf, epss[1], &prm[4 * CH], t);
    for (int i = t; i < (CH * CH) / 4; i += 512)
        ((float4*)w)[i] = ((const float4*)W2_1)[i];
    __syncthreads();

    // h1 = leaky(bn(A1 @ W2_1 + b2_1)), in place in bufA
    gemm_inplace<true>(bufA, w, &prm[5 * CH], &prm[6 * CH], &prm[7 * CH], t);
    __syncthreads();

    pool_store(bufA, psc, t);
    __syncthreads();
    pool_final(psc, z + (size_t)g * 128 + 64, t);
}

// ---------------------------------------------------------------------------
// K4: head MLP  z[512,128] -> 256 -> 128 -> 1
// ---------------------------------------------------------------------------
__global__ __launch_bounds__(256) void k_head(
    const float* __restrict__ z, const float* __restrict__ W1,
    const float* __restrict__ b1, const float* __restrict__ g1,
    const float* __restrict__ be1, const float* __restrict__ m1,
    const float* __restrict__ v1, const float* __restrict__ W2,
    const float* __restrict__ b2, const float* __restrict__ g2,
    const float* __restrict__ be2, const float* __restrict__ m2,
    const float* __restrict__ v2, const float* __restrict__ W3,
    const float* __restrict__ b3, float* __restrict__ out) {
    __shared__ float zr[128], z1[256], z2[128];
    const int t = threadIdx.x;
    const int g = blockIdx.x;

    if (t < 32) ((float4*)zr)[t] = ((const float4*)(z + (size_t)g * 128))[t];
    __syncthreads();
    {
        float acc = b1[t];
#pragma unroll 8
        for (int k = 0; k < 128; k++) acc += zr[k] * W1[k * 256 + t];
        float s = g1[t] * rsqrtf(v1[t] + BN_EPS);
        acc = (acc - m1[t]) * s + be1[t];
        z1[t] = leakyf(acc);
    }
    __syncthreads();
    if (t < 128) {
        float acc = b2[t];
#pragma unroll 8
        for (int k = 0; k < 256; k++) acc += z1[k] * W2[k * 128 + t];
        float s = g2[t] * rsqrtf(v2[t] + BN_EPS);
        acc = (acc - m2[t]) * s + be2[t];
        z2[t] = leakyf(acc);
    }
    __syncthreads();
    if (t < 64) {
        float v = z2[t] * W3[t] + z2[t + 64] * W3[t + 64];
        for (int offd = 32; offd; offd >>= 1) v += __shfl_down(v, offd);
        if (t == 0) out[g] = v + b3[0];
    }
}

// ---------------------------------------------------------------------------
extern "C" void kernel_launch(void* const* d_in, const int* in_sizes, int n_in,
                              void* d_out, int out_size, void* d_ws, size_t ws_size,
                              hipStream_t stream) {
    const float* x      = (const float*)d_in[0];
    const int* eidx     = (const int*)d_in[1];
    const float* eps0   = (const float*)d_in[3];
    const float* W1_0   = (const float*)d_in[4];
    const float* b1_0   = (const float*)d_in[5];
    const float* W2_0   = (const float*)d_in[6];
    const float* b2_0   = (const float*)d_in[7];
    const float* bn0_g  = (const float*)d_in[8];
    const float* bn0_b  = (const float*)d_in[9];
    const float* bn0_m  = (const float*)d_in[10];
    const float* bn0_v  = (const float*)d_in[11];
    const float* eps1   = (const float*)d_in[12];
    const float* W1_1   = (const float*)d_in[13];
    const float* b1_1   = (const float*)d_in[14];
    const float* W2_1   = (const float*)d_in[15];
    const float* b2_1   = (const float*)d_in[16];
    const float* bn1_g  = (const float*)d_in[17];
    const float* bn1_b  = (const float*)d_in[18];
    const float* bn1_m  = (const float*)d_in[19];
    const float* bn1_v  = (const float*)d_in[20];
    const float* lin1_W = (const float*)d_in[21];
    const float* lin1_b = (const float*)d_in[22];
    const float* hbn1_g = (const float*)d_in[23];
    const float* hbn1_b = (const float*)d_in[24];
    const float* hbn1_m = (const float*)d_in[25];
    const float* hbn1_v = (const float*)d_in[26];
    const float* lin2_W = (const float*)d_in[27];
    const float* lin2_b = (const float*)d_in[28];
    const float* hbn2_g = (const float*)d_in[29];
    const float* hbn2_b = (const float*)d_in[30];
    const float* hbn2_m = (const float*)d_in[31];
    const float* hbn2_v = (const float*)d_in[32];
    const float* lin3_W = (const float*)d_in[33];
    const float* lin3_b = (const float*)d_in[34];

    const int E = in_sizes[1] / 2;
    const int* src = eidx;
    const int* dst = eidx + E;

    char* ws = (char*)d_ws;
    const size_t Y0_OFF  = 0;
    const size_t Z_OFF   = (size_t)NNODES * CH * 4;          // 17,563,648
    const size_t CNT_OFF = Z_OFF + (size_t)NG * 128 * 4;     // +262,144
    const size_t OFF_OFF = CNT_OFF + NG * 4;                 // +2,048
    const size_t DEG_OFF = OFF_OFF + (NG + 4) * 4;           // off[513] padded
    const size_t RP_OFF  = DEG_OFF + (size_t)NNODES * 4;
    const size_t EB_OFF  = RP_OFF + (size_t)(NNODES + 4) * 4;
    // total ~22.9 MB

    float* y0    = (float*)(ws + Y0_OFF);
    float* z     = (float*)(ws + Z_OFF);
    int* cnt     = (int*)(ws + CNT_OFF);
    int* off     = (int*)(ws + OFF_OFF);
    int* deg     = (int*)(ws + DEG_OFF);   // degree, then reused as fill cursor
    int* row_ptr = (int*)(ws + RP_OFF);
    int* ebuf    = (int*)(ws + EB_OFF);

    k_gemm1<<<NNODES / 256, 256, 0, stream>>>(x, W1_0, y0);

    hipMemsetAsync(cnt, 0, NG * sizeof(int), stream);
    hipMemsetAsync(deg, 0, (size_t)NNODES * sizeof(int), stream);
    k_hist<<<256, 256, 0, stream>>>(dst, E, cnt);
    k_scan<<<1, NG, 0, stream>>>(cnt, off);
    k_deg<<<512, 256, 0, stream>>>(dst, E, deg);
    k_scan_node<<<NG, 512, 0, stream>>>(deg, off, row_ptr);
    k_fill<<<512, 256, 0, stream>>>(src, dst, E, deg, ebuf);

    k_gin<<<NG, 512, 0, stream>>>(y0, row_ptr, ebuf, eps0, b1_0, W2_0, b2_0,
                                  bn0_g, bn0_b, bn0_m, bn0_v, eps1, W1_1, b1_1,
                                  W2_1, b2_1, bn1_g, bn1_b, bn1_m, bn1_v, z);

    k_head<<<NG, 256, 0, stream>>>(z, lin1_W, lin1_b, hbn1_g, hbn1_b, hbn1_m,
                                   hbn1_v, lin2_W, lin2_b, hbn2_g, hbn2_b,
                                   hbn2_m, hbn2_v, lin3_W, lin3_b,
                                   (float*)d_out);
}

// Round 5
// 558.862 us; speedup vs baseline: 1.9778x; 1.0386x over previous
//
#include <hip/hip_runtime.h>

#define ROI 268
#define NG 512
#define NNODES (NG * ROI)   // 137216
#define CH 32
#define SLOPE 0.33f
#define BN_EPS 1e-5f
#define SR 34               // k_gin LDS row stride (words)
#define SAW 132             // k_gemm1 sA stride (words): even (b128-aligned rows)

__device__ __forceinline__ float leakyf(float v) {
    return v > 0.f ? v : SLOPE * v;
}

// ---------------------------------------------------------------------------
// K1: y0[N,32] = x[N,268] @ W1_0[268,32]  (fp32 vector GEMM)
// 128-thread block = 128 rows; per-thread tile 4 rows x 8 cols.
// Chunked-W staging (4KB) + register prefetch of next chunk -> LDS 21KB,
// global latency hidden behind compute.
// ---------------------------------------------------------------------------
__device__ __forceinline__ void k1_loadx(const float* __restrict__ x,
                                         size_t rowbase, int k0, int ksize,
                                         int tid, float4* pf) {
    if (ksize == 32) {
#pragma unroll
        for (int i = 0; i < 8; i++) {
            int f = tid + (i << 7);
            int row = f >> 3, kk = (f & 7) << 2;
            pf[i] = *(const float4*)&x[(rowbase + row) * ROI + k0 + kk];
        }
    } else {   // ksize == 12
#pragma unroll
        for (int i = 0; i < 3; i++)
            pf[i] = *(const float4*)&x[(rowbase + tid) * ROI + k0 + (i << 2)];
    }
}

__device__ __forceinline__ void k1_storex(float* __restrict__ sA, int ksize,
                                          int tid, const float4* pf) {
    if (ksize == 32) {
#pragma unroll
        for (int i = 0; i < 8; i++) {
            int f = tid + (i << 7);
            int row = f >> 3, kk = (f & 7) << 2;
            sA[(kk + 0) * SAW + row] = pf[i].x;
            sA[(kk + 1) * SAW + row] = pf[i].y;
            sA[(kk + 2) * SAW + row] = pf[i].z;
            sA[(kk + 3) * SAW + row] = pf[i].w;
        }
    } else {
#pragma unroll
        for (int i = 0; i < 3; i++) {
            int kk = i << 2;
            sA[(kk + 0) * SAW + tid] = pf[i].x;
            sA[(kk + 1) * SAW + tid] = pf[i].y;
            sA[(kk + 2) * SAW + tid] = pf[i].z;
            sA[(kk + 3) * SAW + tid] = pf[i].w;
        }
    }
}

__global__ __launch_bounds__(128, 4) void k_gemm1(
    const float* __restrict__ x, const float* __restrict__ W1,
    float* __restrict__ y0) {
    __shared__ float sW[32 * CH];     // current k-chunk of W1 (4KB)
    __shared__ float sA[32 * SAW];    // k-major x tile (16.9KB)

    const int tid = threadIdx.x;
    const size_t rowbase = (size_t)blockIdx.x * 128;
    const int rg = tid >> 2;   // 0..31 -> 4 rows each
    const int cg = tid & 3;    // 0..3  -> 8 cols each

    float acc[4][8];
#pragma unroll
    for (int r = 0; r < 4; r++)
#pragma unroll
        for (int c = 0; c < 8; c++) acc[r][c] = 0.f;

    float4 pf[8];
    float4 pw;

    // prefetch chunk 0
    k1_loadx(x, rowbase, 0, 32, tid, pf);
    if (tid < 256) pw = ((const float4*)W1)[tid & 255];   // 32*32/4=256 f4, 128 thr -> 2 rounds
    float4 pw2 = ((const float4*)W1)[tid + 128];

    int k0 = 0;
    for (int chunk = 0; chunk < 9; ++chunk) {
        const int ksize = (chunk < 8) ? 32 : 12;
        // store prefetched chunk to LDS
        k1_storex(sA, ksize, tid, pf);
        {
            int nw4 = (ksize * CH) >> 2;   // 256 or 96
            if (tid < nw4) ((float4*)sW)[tid] = pw;
            if (tid + 128 < nw4) ((float4*)sW)[tid + 128] = pw2;
        }
        __syncthreads();
        // issue next chunk's global loads (in flight during compute)
        if (chunk + 1 < 9) {
            int nk0 = k0 + ksize;
            int nks = (chunk + 1 < 8) ? 32 : 12;
            k1_loadx(x, rowbase, nk0, nks, tid, pf);
            int nw4 = (nks * CH) >> 2;
            if (tid < nw4) pw = ((const float4*)(W1 + nk0 * CH))[tid];
            if (tid + 128 < nw4) pw2 = ((const float4*)(W1 + nk0 * CH))[tid + 128];
        }
#pragma unroll 4
        for (int kk = 0; kk < ksize; ++kk) {
            float4 a4 = *(float4*)&sA[kk * SAW + rg * 4];
            const float* wr = &sW[kk * CH + cg * 8];
            float4 w0 = *(const float4*)wr;
            float4 w1 = *(const float4*)(wr + 4);
            float av[4] = {a4.x, a4.y, a4.z, a4.w};
            float wv[8] = {w0.x, w0.y, w0.z, w0.w, w1.x, w1.y, w1.z, w1.w};
#pragma unroll
            for (int r = 0; r < 4; r++)
#pragma unroll
                for (int c = 0; c < 8; c++) acc[r][c] += av[r] * wv[c];
        }
        k0 += ksize;
        __syncthreads();
    }

#pragma unroll
    for (int r = 0; r < 4; r++) {
        size_t row = rowbase + rg * 4 + r;
        *(float4*)&y0[row * CH + cg * 8] =
            make_float4(acc[r][0], acc[r][1], acc[r][2], acc[r][3]);
        *(float4*)&y0[row * CH + cg * 8 + 4] =
            make_float4(acc[r][4], acc[r][5], acc[r][6], acc[r][7]);
    }
}

// ---------------------------------------------------------------------------
// K2: CSR build (by dst node). deg -> in-place local scan -> graph scan ->
// finalize (add bases, init cursors) -> fill.
// ---------------------------------------------------------------------------
__global__ void k_deg(const int* __restrict__ dst, int E, int* __restrict__ deg) {
    int stride = gridDim.x * blockDim.x;
    for (int i = blockIdx.x * blockDim.x + threadIdx.x; i < E; i += stride)
        atomicAdd(&deg[dst[i]], 1);
}

// per-graph exclusive scan of node degrees, in place; cnt[g] = graph total
__global__ __launch_bounds__(512) void k_scan_local(
    int* __restrict__ deg, int* __restrict__ cnt) {
    __shared__ int s[512];
    const int g = blockIdx.x, t = threadIdx.x;
    int v = (t < ROI) ? deg[g * ROI + t] : 0;
    s[t] = v;
    __syncthreads();
    for (int d = 1; d < 512; d <<= 1) {
        int u = (t >= d) ? s[t - d] : 0;
        __syncthreads();
        s[t] += u;
        __syncthreads();
    }
    if (t < ROI) deg[g * ROI + t] = s[t] - v;   // exclusive, graph-local
    if (t == 511) cnt[g] = s[511];
}

__global__ void k_scan(const int* __restrict__ cnt, int* __restrict__ off) {
    __shared__ int s[NG];
    int t = threadIdx.x;   // 512 threads
    int myc = cnt[t];
    s[t] = myc;
    __syncthreads();
    for (int d = 1; d < NG; d <<= 1) {
        int v = (t >= d) ? s[t - d] : 0;
        __syncthreads();
        s[t] += v;
        __syncthreads();
    }
    off[t] = s[t] - myc;
    if (t == NG - 1) off[NG] = s[t];
}

// row_ptr = local + off[g]; deg becomes the fill cursor
__global__ __launch_bounds__(512) void k_finalize(
    int* __restrict__ deg, const int* __restrict__ off,
    int* __restrict__ row_ptr) {
    const int g = blockIdx.x, t = threadIdx.x;
    if (t < ROI) {
        int v = deg[g * ROI + t] + off[g];
        row_ptr[g * ROI + t] = v;
        deg[g * ROI + t] = v;
    }
    if (g == 0 && t == 0) row_ptr[NNODES] = off[NG];
}

__global__ void k_fill(const int* __restrict__ src, const int* __restrict__ dst,
                       int E, int* __restrict__ rcur, int* __restrict__ ebuf) {
    int stride = gridDim.x * blockDim.x;
    for (int i = blockIdx.x * blockDim.x + threadIdx.x; i < E; i += stride) {
        int d = dst[i];
        int g = d / ROI;
        int pos = atomicAdd(&rcur[d], 1);
        ebuf[pos] = (src[i] - g * ROI) * SR;   // premultiplied LDS word offset
    }
}

// ---------------------------------------------------------------------------
// K3 helpers
// ---------------------------------------------------------------------------
__device__ __forceinline__ void gather_combine(
    const float* __restrict__ in, float* __restrict__ out,
    const int* __restrict__ rp, const int* __restrict__ ebuf, float e,
    const float* __restrict__ b1, int t) {
    const int ch = t & 31;
    const int hw = t >> 5;   // 0..15
    for (int n = hw; n < ROI; n += 16) {
        int b = rp[n], en = rp[n + 1];
        float acc = 0.f;
        int j = b;
        for (; j + 3 < en; j += 4) {
            int p0 = ebuf[j], p1 = ebuf[j + 1], p2 = ebuf[j + 2], p3 = ebuf[j + 3];
            float v0 = in[p0 + ch], v1 = in[p1 + ch];
            float v2 = in[p2 + ch], v3 = in[p3 + ch];
            acc += (v0 + v1) + (v2 + v3);
        }
        for (; j < en; ++j) acc += in[ebuf[j] + ch];
        out[n * SR + ch] = leakyf(e * in[n * SR + ch] + acc + b1[ch]);
    }
}

template <bool AFFINE>
__device__ __forceinline__ void gemm_inplace(float* __restrict__ buf,
                                             const float* __restrict__ w,
                                             const float* __restrict__ bias,
                                             const float* __restrict__ sc,
                                             const float* __restrict__ sh, int t) {
    for (int u = t; u < ROI * 2; u += 512) {
        const int r0 = (u >> 2) * 2;
        const int cq = u & 3;
        float acc0[8], acc1[8];
#pragma unroll
        for (int c = 0; c < 8; c++) {
            float b = AFFINE ? bias[cq * 8 + c] : 0.f;
            acc0[c] = b;
            acc1[c] = b;
        }
        const float* row0 = &buf[r0 * SR];
        const float* row1 = row0 + SR;
        // unroll 2 ONLY: full unroll software-pipelines all 64 w-float4s
        // -> >128 VGPR -> scratch spill -> 1 GB HBM (rounds 2/3)
#pragma unroll 2
        for (int k = 0; k < CH; k += 2) {
            float2 a0 = *(const float2*)&row0[k];
            float2 a1 = *(const float2*)&row1[k];
            const float* wr0 = &w[k * CH + cq * 8];
            const float* wr1 = wr0 + CH;
            float4 wa = *(const float4*)wr0;
            float4 wb = *(const float4*)(wr0 + 4);
            float4 wc = *(const float4*)wr1;
            float4 wd = *(const float4*)(wr1 + 4);
            acc0[0] += a0.x * wa.x + a0.y * wc.x;
            acc0[1] += a0.x * wa.y + a0.y * wc.y;
            acc0[2] += a0.x * wa.z + a0.y * wc.z;
            acc0[3] += a0.x * wa.w + a0.y * wc.w;
            acc0[4] += a0.x * wb.x + a0.y * wd.x;
            acc0[5] += a0.x * wb.y + a0.y * wd.y;
            acc0[6] += a0.x * wb.z + a0.y * wd.z;
            acc0[7] += a0.x * wb.w + a0.y * wd.w;
            acc1[0] += a1.x * wa.x + a1.y * wc.x;
            acc1[1] += a1.x * wa.y + a1.y * wc.y;
            acc1[2] += a1.x * wa.z + a1.y * wc.z;
            acc1[3] += a1.x * wa.w + a1.y * wc.w;
            acc1[4] += a1.x * wb.x + a1.y * wd.x;
            acc1[5] += a1.x * wb.y + a1.y * wd.y;
            acc1[6] += a1.x * wb.z + a1.y * wd.z;
            acc1[7] += a1.x * wb.w + a1.y * wd.w;
        }
        float* o0 = &buf[r0 * SR + cq * 8];
        float* o1 = o0 + SR;
#pragma unroll
        for (int c = 0; c < 8; c += 2) {
            float h00 = acc0[c], h01 = acc0[c + 1];
            float h10 = acc1[c], h11 = acc1[c + 1];
            if (AFFINE) {
                float s0 = sc[cq * 8 + c], t0 = sh[cq * 8 + c];
                float s1 = sc[cq * 8 + c + 1], t1 = sh[cq * 8 + c + 1];
                h00 = leakyf(h00 * s0 + t0);
                h01 = leakyf(h01 * s1 + t1);
                h10 = leakyf(h10 * s0 + t0);
                h11 = leakyf(h11 * s1 + t1);
            }
            *(float2*)&o0[c] = make_float2(h00, h01);
            *(float2*)&o1[c] = make_float2(h10, h11);
        }
    }
}

__device__ __forceinline__ void pool_store(const float* __restrict__ h,
                                           float* __restrict__ psc, int t) {
    const int ch = t & 31;
    const int hw = t >> 5;
    const int wave = t >> 6;
    float s = 0.f, m = -1e30f;
    for (int n = hw; n < ROI; n += 16) {
        float v = h[n * SR + ch];
        s += v;
        m = fmaxf(m, v);
    }
    s += __shfl_down(s, 32);
    m = fmaxf(m, __shfl_down(m, 32));
    if ((t & 63) < 32) {
        psc[wave * 32 + ch] = s;
        psc[256 + wave * 32 + ch] = m;
    }
}

__device__ __forceinline__ void pool_final(const float* __restrict__ psc,
                                           float* __restrict__ zg, int t) {
    if (t < 32) {
        float s = 0.f, m = -1e30f;
#pragma unroll
        for (int wv = 0; wv < 8; wv++) {
            s += psc[wv * 32 + t];
            m = fmaxf(m, psc[256 + wv * 32 + t]);
        }
        zg[t] = m;
        zg[CH + t] = s / (float)ROI;
    }
}

// ---------------------------------------------------------------------------
// K3: fused both GIN layers + both poolings. One 512-thr block per graph.
// ---------------------------------------------------------------------------
__global__ __launch_bounds__(512, 2) void k_gin(
    const float* __restrict__ y0, const int* __restrict__ row_ptr,
    const int* __restrict__ ebuf, const float* __restrict__ eps0p,
    const float* __restrict__ b1_0, const float* __restrict__ W2_0,
    const float* __restrict__ b2_0, const float* __restrict__ bn0_g,
    const float* __restrict__ bn0_b, const float* __restrict__ bn0_m,
    const float* __restrict__ bn0_v, const float* __restrict__ eps1p,
    const float* __restrict__ W1_1, const float* __restrict__ b1_1,
    const float* __restrict__ W2_1, const float* __restrict__ b2_1,
    const float* __restrict__ bn1_g, const float* __restrict__ bn1_b,
    const float* __restrict__ bn1_m, const float* __restrict__ bn1_v,
    float* __restrict__ z) {
    __shared__ float bufA[ROI * SR];
    __shared__ float bufB[ROI * SR];
    __shared__ float w[CH * CH];
    __shared__ float prm[8 * CH];
    __shared__ float psc[512];
    __shared__ float epss[2];

    const int t = threadIdx.x;
    const int g = blockIdx.x;

    if (t < CH) {
        prm[0 * CH + t] = b1_0[t];
        prm[1 * CH + t] = b2_0[t];
        float s0 = bn0_g[t] * rsqrtf(bn0_v[t] + BN_EPS);
        prm[2 * CH + t] = s0;
        prm[3 * CH + t] = bn0_b[t] - bn0_m[t] * s0;
        prm[4 * CH + t] = b1_1[t];
        prm[5 * CH + t] = b2_1[t];
        float s1 = bn1_g[t] * rsqrtf(bn1_v[t] + BN_EPS);
        prm[6 * CH + t] = s1;
        prm[7 * CH + t] = bn1_b[t] - bn1_m[t] * s1;
    }
    if (t == 0) {
        epss[0] = 1.0f + *eps0p;
        epss[1] = 1.0f + *eps1p;
    }

    const float* yg = y0 + (size_t)g * ROI * CH;
    for (int f = t; f < (ROI * CH) / 4; f += 512) {
        float4 v = ((const float4*)yg)[f];
        int row = f >> 3, c4 = (f & 7) << 2;
        float* p = &bufA[row * SR + c4];
        *(float2*)p = make_float2(v.x, v.y);
        *(float2*)(p + 2) = make_float2(v.z, v.w);
    }
    for (int i = t; i < (CH * CH) / 4; i += 512)
        ((float4*)w)[i] = ((const float4*)W2_0)[i];
    __syncthreads();

    const int* rp = row_ptr + g * ROI;

    gather_combine(bufA, bufB, rp, ebuf, epss[0], &prm[0 * CH], t);
    __syncthreads();

    gemm_inplace<true>(bufB, w, &prm[1 * CH], &prm[2 * CH], &prm[3 * CH], t);
    __syncthreads();

    pool_store(bufB, psc, t);
    for (int i = t; i < (CH * CH) / 4; i += 512)
        ((float4*)w)[i] = ((const float4*)W1_1)[i];
    __syncthreads();

    pool_final(psc, z + (size_t)g * 128, t);
    gemm_inplace<false>(bufB, w, nullptr, nullptr, nullptr, t);
    __syncthreads();

    gather_combine(bufB, bufA, rp, ebuf, epss[1], &prm[4 * CH], t);
    for (int i = t; i < (CH * CH) / 4; i += 512)
        ((float4*)w)[i] = ((const float4*)W2_1)[i];
    __syncthreads();

    gemm_inplace<true>(bufA, w, &prm[5 * CH], &prm[6 * CH], &prm[7 * CH], t);
    __syncthreads();

    pool_store(bufA, psc, t);
    __syncthreads();
    pool_final(psc, z + (size_t)g * 128 + 64, t);
}

// ---------------------------------------------------------------------------
// K4: head MLP  z[512,128] -> 256 -> 128 -> 1
// ---------------------------------------------------------------------------
__global__ __launch_bounds__(256) void k_head(
    const float* __restrict__ z, const float* __restrict__ W1,
    const float* __restrict__ b1, const float* __restrict__ g1,
    const float* __restrict__ be1, const float* __restrict__ m1,
    const float* __restrict__ v1, const float* __restrict__ W2,
    const float* __restrict__ b2, const float* __restrict__ g2,
    const float* __restrict__ be2, const float* __restrict__ m2,
    const float* __restrict__ v2, const float* __restrict__ W3,
    const float* __restrict__ b3, float* __restrict__ out) {
    __shared__ float zr[128], z1[256], z2[128];
    const int t = threadIdx.x;
    const int g = blockIdx.x;

    if (t < 32) ((float4*)zr)[t] = ((const float4*)(z + (size_t)g * 128))[t];
    __syncthreads();
    {
        float acc = b1[t];
#pragma unroll 8
        for (int k = 0; k < 128; k++) acc += zr[k] * W1[k * 256 + t];
        float s = g1[t] * rsqrtf(v1[t] + BN_EPS);
        acc = (acc - m1[t]) * s + be1[t];
        z1[t] = leakyf(acc);
    }
    __syncthreads();
    if (t < 128) {
        float acc = b2[t];
#pragma unroll 8
        for (int k = 0; k < 256; k++) acc += z1[k] * W2[k * 128 + t];
        float s = g2[t] * rsqrtf(v2[t] + BN_EPS);
        acc = (acc - m2[t]) * s + be2[t];
        z2[t] = leakyf(acc);
    }
    __syncthreads();
    if (t < 64) {
        float v = z2[t] * W3[t] + z2[t + 64] * W3[t + 64];
        for (int offd = 32; offd; offd >>= 1) v += __shfl_down(v, offd);
        if (t == 0) out[g] = v + b3[0];
    }
}

// ---------------------------------------------------------------------------
extern "C" void kernel_launch(void* const* d_in, const int* in_sizes, int n_in,
                              void* d_out, int out_size, void* d_ws, size_t ws_size,
                              hipStream_t stream) {
    const float* x      = (const float*)d_in[0];
    const int* eidx     = (const int*)d_in[1];
    const float* eps0   = (const float*)d_in[3];
    const float* W1_0   = (const float*)d_in[4];
    const float* b1_0   = (const float*)d_in[5];
    const float* W2_0   = (const float*)d_in[6];
    const float* b2_0   = (const float*)d_in[7];
    const float* bn0_g  = (const float*)d_in[8];
    const float* bn0_b  = (const float*)d_in[9];
    const float* bn0_m  = (const float*)d_in[10];
    const float* bn0_v  = (const float*)d_in[11];
    const float* eps1   = (const float*)d_in[12];
    const float* W1_1   = (const float*)d_in[13];
    const float* b1_1   = (const float*)d_in[14];
    const float* W2_1   = (const float*)d_in[15];
    const float* b2_1   = (const float*)d_in[16];
    const float* bn1_g  = (const float*)d_in[17];
    const float* bn1_b  = (const float*)d_in[18];
    const float* bn1_m  = (const float*)d_in[19];
    const float* bn1_v  = (const float*)d_in[20];
    const float* lin1_W = (const float*)d_in[21];
    const float* lin1_b = (const float*)d_in[22];
    const float* hbn1_g = (const float*)d_in[23];
    const float* hbn1_b = (const float*)d_in[24];
    const float* hbn1_m = (const float*)d_in[25];
    const float* hbn1_v = (const float*)d_in[26];
    const float* lin2_W = (const float*)d_in[27];
    const float* lin2_b = (const float*)d_in[28];
    const float* hbn2_g = (const float*)d_in[29];
    const float* hbn2_b = (const float*)d_in[30];
    const float* hbn2_m = (const float*)d_in[31];
    const float* hbn2_v = (const float*)d_in[32];
    const float* lin3_W = (const float*)d_in[33];
    const float* lin3_b = (const float*)d_in[34];

    const int E = in_sizes[1] / 2;
    const int* src = eidx;
    const int* dst = eidx + E;

    char* ws = (char*)d_ws;
    const size_t Y0_OFF  = 0;
    const size_t Z_OFF   = (size_t)NNODES * CH * 4;          // 17,563,648
    const size_t CNT_OFF = Z_OFF + (size_t)NG * 128 * 4;
    const size_t OFF_OFF = CNT_OFF + NG * 4;
    const size_t DEG_OFF = OFF_OFF + (NG + 4) * 4;
    const size_t RP_OFF  = DEG_OFF + (size_t)NNODES * 4;
    const size_t EB_OFF  = RP_OFF + (size_t)(NNODES + 4) * 4;

    float* y0    = (float*)(ws + Y0_OFF);
    float* z     = (float*)(ws + Z_OFF);
    int* cnt     = (int*)(ws + CNT_OFF);
    int* off     = (int*)(ws + OFF_OFF);
    int* deg     = (int*)(ws + DEG_OFF);   // degree -> local scan -> cursor
    int* row_ptr = (int*)(ws + RP_OFF);
    int* ebuf    = (int*)(ws + EB_OFF);

    k_gemm1<<<NNODES / 128, 128, 0, stream>>>(x, W1_0, y0);

    hipMemsetAsync(deg, 0, (size_t)NNODES * sizeof(int), stream);
    k_deg<<<1024, 256, 0, stream>>>(dst, E, deg);
    k_scan_local<<<NG, 512, 0, stream>>>(deg, cnt);
    k_scan<<<1, NG, 0, stream>>>(cnt, off);
    k_finalize<<<NG, 512, 0, stream>>>(deg, off, row_ptr);
    k_fill<<<1024, 256, 0, stream>>>(src, dst, E, deg, ebuf);

    k_gin<<<NG, 512, 0, stream>>>(y0, row_ptr, ebuf, eps0, b1_0, W2_0, b2_0,
                                  bn0_g, bn0_b, bn0_m, bn0_v, eps1, W1_1, b1_1,
                                  W2_1, b2_1, bn1_g, bn1_b, bn1_m, bn1_v, z);

    k_head<<<NG, 256, 0, stream>>>(z, lin1_W, lin1_b, hbn1_g, hbn1_b, hbn1_m,
                                   hbn1_v, lin2_W, lin2_b, hbn2_g, hbn2_b,
                                   hbn2_m, hbn2_v, lin3_W, lin3_b,
                                   (float*)d_out);
}

// Round 6
// 553.838 us; speedup vs baseline: 1.9957x; 1.0091x over previous
//
#include <hip/hip_runtime.h>

#define ROI 268
#define NG 512
#define NNODES (NG * ROI)   // 137216
#define CH 32
#define SLOPE 0.33f
#define BN_EPS 1e-5f
#define SR 34               // k_gin LDS row stride (words)
#define SAW 134             // k_gemm1 sA stride: mod32=6 -> stores/reads <=2-way (free)
#define RPS (ROI + 1)       // row_ptr per-graph stride

__device__ __forceinline__ float leakyf(float v) {
    return v > 0.f ? v : SLOPE * v;
}

// ---------------------------------------------------------------------------
// K1: y0[N,32] = x[N,268] @ W1_0[268,32]  (fp32 vector GEMM)
// 128-thread block = 128 rows; per-thread tile 4 rows x 8 cols.
// Chunked-W staging (4KB) + register prefetch of next chunk.
// launch_bounds(128,2): VGPR cap 256. (128,4) made the allocator chase the
// 64-VGPR tier -> 142MB scratch spill (round 5). Need ~110 VGPR live.
// ---------------------------------------------------------------------------
__device__ __forceinline__ void k1_loadx(const float* __restrict__ x,
                                         size_t rowbase, int k0, int ksize,
                                         int tid, float4* pf) {
    if (ksize == 32) {
#pragma unroll
        for (int i = 0; i < 8; i++) {
            int f = tid + (i << 7);
            int row = f >> 3, kk = (f & 7) << 2;
            pf[i] = *(const float4*)&x[(rowbase + row) * ROI + k0 + kk];
        }
    } else {   // ksize == 12
#pragma unroll
        for (int i = 0; i < 3; i++)
            pf[i] = *(const float4*)&x[(rowbase + tid) * ROI + k0 + (i << 2)];
    }
}

__device__ __forceinline__ void k1_storex(float* __restrict__ sA, int ksize,
                                          int tid, const float4* pf) {
    if (ksize == 32) {
#pragma unroll
        for (int i = 0; i < 8; i++) {
            int f = tid + (i << 7);
            int row = f >> 3, kk = (f & 7) << 2;
            sA[(kk + 0) * SAW + row] = pf[i].x;
            sA[(kk + 1) * SAW + row] = pf[i].y;
            sA[(kk + 2) * SAW + row] = pf[i].z;
            sA[(kk + 3) * SAW + row] = pf[i].w;
        }
    } else {
#pragma unroll
        for (int i = 0; i < 3; i++) {
            int kk = i << 2;
            sA[(kk + 0) * SAW + tid] = pf[i].x;
            sA[(kk + 1) * SAW + tid] = pf[i].y;
            sA[(kk + 2) * SAW + tid] = pf[i].z;
            sA[(kk + 3) * SAW + tid] = pf[i].w;
        }
    }
}

__global__ __launch_bounds__(128, 2) void k_gemm1(
    const float* __restrict__ x, const float* __restrict__ W1,
    float* __restrict__ y0) {
    __shared__ float sW[32 * CH];     // current k-chunk of W1 (4KB)
    __shared__ float sA[32 * SAW];    // k-major x tile (17.2KB)

    const int tid = threadIdx.x;
    const size_t rowbase = (size_t)blockIdx.x * 128;
    const int rg = tid >> 2;   // 0..31 -> 4 rows each
    const int cg = tid & 3;    // 0..3  -> 8 cols each

    float acc[4][8];
#pragma unroll
    for (int r = 0; r < 4; r++)
#pragma unroll
        for (int c = 0; c < 8; c++) acc[r][c] = 0.f;

    float4 pf[8];
    float4 pw, pw2;

    // prefetch chunk 0
    k1_loadx(x, rowbase, 0, 32, tid, pf);
    pw = ((const float4*)W1)[tid];
    pw2 = ((const float4*)W1)[tid + 128];

    int k0 = 0;
    for (int chunk = 0; chunk < 9; ++chunk) {
        const int ksize = (chunk < 8) ? 32 : 12;
        // store prefetched chunk to LDS
        k1_storex(sA, ksize, tid, pf);
        {
            int nw4 = (ksize * CH) >> 2;   // 256 or 96
            if (tid < nw4) ((float4*)sW)[tid] = pw;
            if (tid + 128 < nw4) ((float4*)sW)[tid + 128] = pw2;
        }
        __syncthreads();
        // issue next chunk's global loads (in flight during compute)
        if (chunk + 1 < 9) {
            int nk0 = k0 + ksize;
            int nks = (chunk + 1 < 8) ? 32 : 12;
            k1_loadx(x, rowbase, nk0, nks, tid, pf);
            int nw4 = (nks * CH) >> 2;
            if (tid < nw4) pw = ((const float4*)(W1 + nk0 * CH))[tid];
            if (tid + 128 < nw4) pw2 = ((const float4*)(W1 + nk0 * CH))[tid + 128];
        }
#pragma unroll 4
        for (int kk = 0; kk < ksize; ++kk) {
            float4 a4 = *(float4*)&sA[kk * SAW + rg * 4];
            const float* wr = &sW[kk * CH + cg * 8];
            float4 w0 = *(const float4*)wr;
            float4 w1 = *(const float4*)(wr + 4);
            float av[4] = {a4.x, a4.y, a4.z, a4.w};
            float wv[8] = {w0.x, w0.y, w0.z, w0.w, w1.x, w1.y, w1.z, w1.w};
#pragma unroll
            for (int r = 0; r < 4; r++)
#pragma unroll
                for (int c = 0; c < 8; c++) acc[r][c] += av[r] * wv[c];
        }
        k0 += ksize;
        __syncthreads();
    }

#pragma unroll
    for (int r = 0; r < 4; r++) {
        size_t row = rowbase + rg * 4 + r;
        *(float4*)&y0[row * CH + cg * 8] =
            make_float4(acc[r][0], acc[r][1], acc[r][2], acc[r][3]);
        *(float4*)&y0[row * CH + cg * 8 + 4] =
            make_float4(acc[r][4], acc[r][5], acc[r][6], acc[r][7]);
    }
}

// ---------------------------------------------------------------------------
// K2: CSR build (by dst node): deg -> per-graph scan + atomic base ticket ->
// fill. row_ptr layout [NG][ROI+1] so per-graph bases are order-free.
// ---------------------------------------------------------------------------
__global__ void k_deg(const int* __restrict__ dst, int E, int* __restrict__ deg) {
    int stride = gridDim.x * blockDim.x;
    for (int i = blockIdx.x * blockDim.x + threadIdx.x; i < E; i += stride)
        atomicAdd(&deg[dst[i]], 1);
}

__global__ __launch_bounds__(512) void k_scan_local(
    int* __restrict__ deg, int* __restrict__ ticket, int* __restrict__ row_ptr) {
    __shared__ int s[512];
    __shared__ int sbase;
    const int g = blockIdx.x, t = threadIdx.x;
    int v = (t < ROI) ? deg[g * ROI + t] : 0;
    s[t] = v;
    __syncthreads();
    for (int d = 1; d < 512; d <<= 1) {
        int u = (t >= d) ? s[t - d] : 0;
        __syncthreads();
        s[t] += u;
        __syncthreads();
    }
    if (t == 511) sbase = atomicAdd(ticket, s[511]);
    __syncthreads();
    const int base = sbase;
    if (t < ROI) {
        int exc = base + s[t] - v;
        row_ptr[g * RPS + t] = exc;
        deg[g * ROI + t] = exc;   // becomes fill cursor
    }
    if (t == 511) row_ptr[g * RPS + ROI] = base + s[511];
}

__global__ void k_fill(const int* __restrict__ src, const int* __restrict__ dst,
                       int E, int* __restrict__ rcur, int* __restrict__ ebuf) {
    int stride = gridDim.x * blockDim.x;
    for (int i = blockIdx.x * blockDim.x + threadIdx.x; i < E; i += stride) {
        int d = dst[i];
        int g = d / ROI;
        int pos = atomicAdd(&rcur[d], 1);
        ebuf[pos] = (src[i] - g * ROI) * SR;   // premultiplied LDS word offset
    }
}

// ---------------------------------------------------------------------------
// K3 helpers
// ---------------------------------------------------------------------------
__device__ __forceinline__ void gather_combine(
    const float* __restrict__ in, float* __restrict__ out,
    const int* __restrict__ rp, const int* __restrict__ ebuf, float e,
    const float* __restrict__ b1, int t) {
    const int ch = t & 31;
    const int hw = t >> 5;   // 0..15
    for (int n = hw; n < ROI; n += 16) {
        int b = rp[n], en = rp[n + 1];
        float acc = 0.f;
        int j = b;
        for (; j + 3 < en; j += 4) {
            int p0 = ebuf[j], p1 = ebuf[j + 1], p2 = ebuf[j + 2], p3 = ebuf[j + 3];
            float v0 = in[p0 + ch], v1 = in[p1 + ch];
            float v2 = in[p2 + ch], v3 = in[p3 + ch];
            acc += (v0 + v1) + (v2 + v3);
        }
        for (; j < en; ++j) acc += in[ebuf[j] + ch];
        out[n * SR + ch] = leakyf(e * in[n * SR + ch] + acc + b1[ch]);
    }
}

template <bool AFFINE>
__device__ __forceinline__ void gemm_inplace(float* __restrict__ buf,
                                             const float* __restrict__ w,
                                             const float* __restrict__ bias,
                                             const float* __restrict__ sc,
                                             const float* __restrict__ sh, int t) {
    for (int u = t; u < ROI * 2; u += 512) {
        const int r0 = (u >> 2) * 2;
        const int cq = u & 3;
        float acc0[8], acc1[8];
#pragma unroll
        for (int c = 0; c < 8; c++) {
            float b = AFFINE ? bias[cq * 8 + c] : 0.f;
            acc0[c] = b;
            acc1[c] = b;
        }
        const float* row0 = &buf[r0 * SR];
        const float* row1 = row0 + SR;
        // unroll 2 ONLY: full unroll software-pipelines all 64 w-float4s
        // -> >128 VGPR -> scratch spill -> 1 GB HBM (rounds 2/3)
#pragma unroll 2
        for (int k = 0; k < CH; k += 2) {
            float2 a0 = *(const float2*)&row0[k];
            float2 a1 = *(const float2*)&row1[k];
            const float* wr0 = &w[k * CH + cq * 8];
            const float* wr1 = wr0 + CH;
            float4 wa = *(const float4*)wr0;
            float4 wb = *(const float4*)(wr0 + 4);
            float4 wc = *(const float4*)wr1;
            float4 wd = *(const float4*)(wr1 + 4);
            acc0[0] += a0.x * wa.x + a0.y * wc.x;
            acc0[1] += a0.x * wa.y + a0.y * wc.y;
            acc0[2] += a0.x * wa.z + a0.y * wc.z;
            acc0[3] += a0.x * wa.w + a0.y * wc.w;
            acc0[4] += a0.x * wb.x + a0.y * wd.x;
            acc0[5] += a0.x * wb.y + a0.y * wd.y;
            acc0[6] += a0.x * wb.z + a0.y * wd.z;
            acc0[7] += a0.x * wb.w + a0.y * wd.w;
            acc1[0] += a1.x * wa.x + a1.y * wc.x;
            acc1[1] += a1.x * wa.y + a1.y * wc.y;
            acc1[2] += a1.x * wa.z + a1.y * wc.z;
            acc1[3] += a1.x * wa.w + a1.y * wc.w;
            acc1[4] += a1.x * wb.x + a1.y * wd.x;
            acc1[5] += a1.x * wb.y + a1.y * wd.y;
            acc1[6] += a1.x * wb.z + a1.y * wd.z;
            acc1[7] += a1.x * wb.w + a1.y * wd.w;
        }
        float* o0 = &buf[r0 * SR + cq * 8];
        float* o1 = o0 + SR;
#pragma unroll
        for (int c = 0; c < 8; c += 2) {
            float h00 = acc0[c], h01 = acc0[c + 1];
            float h10 = acc1[c], h11 = acc1[c + 1];
            if (AFFINE) {
                float s0 = sc[cq * 8 + c], t0 = sh[cq * 8 + c];
                float s1 = sc[cq * 8 + c + 1], t1 = sh[cq * 8 + c + 1];
                h00 = leakyf(h00 * s0 + t0);
                h01 = leakyf(h01 * s1 + t1);
                h10 = leakyf(h10 * s0 + t0);
                h11 = leakyf(h11 * s1 + t1);
            }
            *(float2*)&o0[c] = make_float2(h00, h01);
            *(float2*)&o1[c] = make_float2(h10, h11);
        }
    }
}

__device__ __forceinline__ void pool_store(const float* __restrict__ h,
                                           float* __restrict__ psc, int t) {
    const int ch = t & 31;
    const int hw = t >> 5;
    const int wave = t >> 6;
    float s = 0.f, m = -1e30f;
    for (int n = hw; n < ROI; n += 16) {
        float v = h[n * SR + ch];
        s += v;
        m = fmaxf(m, v);
    }
    s += __shfl_down(s, 32);
    m = fmaxf(m, __shfl_down(m, 32));
    if ((t & 63) < 32) {
        psc[wave * 32 + ch] = s;
        psc[256 + wave * 32 + ch] = m;
    }
}

__device__ __forceinline__ void pool_final(const float* __restrict__ psc,
                                           float* __restrict__ zg, int t) {
    if (t < 32) {
        float s = 0.f, m = -1e30f;
#pragma unroll
        for (int wv = 0; wv < 8; wv++) {
            s += psc[wv * 32 + t];
            m = fmaxf(m, psc[256 + wv * 32 + t]);
        }
        zg[t] = m;
        zg[CH + t] = s / (float)ROI;
    }
}

// ---------------------------------------------------------------------------
// K3: fused both GIN layers + both poolings. One 512-thr block per graph.
// ---------------------------------------------------------------------------
__global__ __launch_bounds__(512, 2) void k_gin(
    const float* __restrict__ y0, const int* __restrict__ row_ptr,
    const int* __restrict__ ebuf, const float* __restrict__ eps0p,
    const float* __restrict__ b1_0, const float* __restrict__ W2_0,
    const float* __restrict__ b2_0, const float* __restrict__ bn0_g,
    const float* __restrict__ bn0_b, const float* __restrict__ bn0_m,
    const float* __restrict__ bn0_v, const float* __restrict__ eps1p,
    const float* __restrict__ W1_1, const float* __restrict__ b1_1,
    const float* __restrict__ W2_1, const float* __restrict__ b2_1,
    const float* __restrict__ bn1_g, const float* __restrict__ bn1_b,
    const float* __restrict__ bn1_m, const float* __restrict__ bn1_v,
    float* __restrict__ z) {
    __shared__ float bufA[ROI * SR];
    __shared__ float bufB[ROI * SR];
    __shared__ float w[CH * CH];
    __shared__ float prm[8 * CH];
    __shared__ float psc[512];
    __shared__ float epss[2];

    const int t = threadIdx.x;
    const int g = blockIdx.x;

    if (t < CH) {
        prm[0 * CH + t] = b1_0[t];
        prm[1 * CH + t] = b2_0[t];
        float s0 = bn0_g[t] * rsqrtf(bn0_v[t] + BN_EPS);
        prm[2 * CH + t] = s0;
        prm[3 * CH + t] = bn0_b[t] - bn0_m[t] * s0;
        prm[4 * CH + t] = b1_1[t];
        prm[5 * CH + t] = b2_1[t];
        float s1 = bn1_g[t] * rsqrtf(bn1_v[t] + BN_EPS);
        prm[6 * CH + t] = s1;
        prm[7 * CH + t] = bn1_b[t] - bn1_m[t] * s1;
    }
    if (t == 0) {
        epss[0] = 1.0f + *eps0p;
        epss[1] = 1.0f + *eps1p;
    }

    const float* yg = y0 + (size_t)g * ROI * CH;
    for (int f = t; f < (ROI * CH) / 4; f += 512) {
        float4 v = ((const float4*)yg)[f];
        int row = f >> 3, c4 = (f & 7) << 2;
        float* p = &bufA[row * SR + c4];
        *(float2*)p = make_float2(v.x, v.y);
        *(float2*)(p + 2) = make_float2(v.z, v.w);
    }
    for (int i = t; i < (CH * CH) / 4; i += 512)
        ((float4*)w)[i] = ((const float4*)W2_0)[i];
    __syncthreads();

    const int* rp = row_ptr + g * RPS;

    gather_combine(bufA, bufB, rp, ebuf, epss[0], &prm[0 * CH], t);
    __syncthreads();

    gemm_inplace<true>(bufB, w, &prm[1 * CH], &prm[2 * CH], &prm[3 * CH], t);
    __syncthreads();

    pool_store(bufB, psc, t);
    for (int i = t; i < (CH * CH) / 4; i += 512)
        ((float4*)w)[i] = ((const float4*)W1_1)[i];
    __syncthreads();

    pool_final(psc, z + (size_t)g * 128, t);
    gemm_inplace<false>(bufB, w, nullptr, nullptr, nullptr, t);
    __syncthreads();

    gather_combine(bufB, bufA, rp, ebuf, epss[1], &prm[4 * CH], t);
    for (int i = t; i < (CH * CH) / 4; i += 512)
        ((float4*)w)[i] = ((const float4*)W2_1)[i];
    __syncthreads();

    gemm_inplace<true>(bufA, w, &prm[5 * CH], &prm[6 * CH], &prm[7 * CH], t);
    __syncthreads();

    pool_store(bufA, psc, t);
    __syncthreads();
    pool_final(psc, z + (size_t)g * 128 + 64, t);
}

// ---------------------------------------------------------------------------
// K4: head MLP  z[512,128] -> 256 -> 128 -> 1
// ---------------------------------------------------------------------------
__global__ __launch_bounds__(256) void k_head(
    const float* __restrict__ z, const float* __restrict__ W1,
    const float* __restrict__ b1, const float* __restrict__ g1,
    const float* __restrict__ be1, const float* __restrict__ m1,
    const float* __restrict__ v1, const float* __restrict__ W2,
    const float* __restrict__ b2, const float* __restrict__ g2,
    const float* __restrict__ be2, const float* __restrict__ m2,
    const float* __restrict__ v2, const float* __restrict__ W3,
    const float* __restrict__ b3, float* __restrict__ out) {
    __shared__ float zr[128], z1[256], z2[128];
    const int t = threadIdx.x;
    const int g = blockIdx.x;

    if (t < 32) ((float4*)zr)[t] = ((const float4*)(z + (size_t)g * 128))[t];
    __syncthreads();
    {
        float acc = b1[t];
#pragma unroll 8
        for (int k = 0; k < 128; k++) acc += zr[k] * W1[k * 256 + t];
        float s = g1[t] * rsqrtf(v1[t] + BN_EPS);
        acc = (acc - m1[t]) * s + be1[t];
        z1[t] = leakyf(acc);
    }
    __syncthreads();
    if (t < 128) {
        float acc = b2[t];
#pragma unroll 8
        for (int k = 0; k < 256; k++) acc += z1[k] * W2[k * 128 + t];
        float s = g2[t] * rsqrtf(v2[t] + BN_EPS);
        acc = (acc - m2[t]) * s + be2[t];
        z2[t] = leakyf(acc);
    }
    __syncthreads();
    if (t < 64) {
        float v = z2[t] * W3[t] + z2[t + 64] * W3[t + 64];
        for (int offd = 32; offd; offd >>= 1) v += __shfl_down(v, offd);
        if (t == 0) out[g] = v + b3[0];
    }
}

// ---------------------------------------------------------------------------
extern "C" void kernel_launch(void* const* d_in, const int* in_sizes, int n_in,
                              void* d_out, int out_size, void* d_ws, size_t ws_size,
                              hipStream_t stream) {
    const float* x      = (const float*)d_in[0];
    const int* eidx     = (const int*)d_in[1];
    const float* eps0   = (const float*)d_in[3];
    const float* W1_0   = (const float*)d_in[4];
    const float* b1_0   = (const float*)d_in[5];
    const float* W2_0   = (const float*)d_in[6];
    const float* b2_0   = (const float*)d_in[7];
    const float* bn0_g  = (const float*)d_in[8];
    const float* bn0_b  = (const float*)d_in[9];
    const float* bn0_m  = (const float*)d_in[10];
    const float* bn0_v  = (const float*)d_in[11];
    const float* eps1   = (const float*)d_in[12];
    const float* W1_1   = (const float*)d_in[13];
    const float* b1_1   = (const float*)d_in[14];
    const float* W2_1   = (const float*)d_in[15];
    const float* b2_1   = (const float*)d_in[16];
    const float* bn1_g  = (const float*)d_in[17];
    const float* bn1_b  = (const float*)d_in[18];
    const float* bn1_m  = (const float*)d_in[19];
    const float* bn1_v  = (const float*)d_in[20];
    const float* lin1_W = (const float*)d_in[21];
    const float* lin1_b = (const float*)d_in[22];
    const float* hbn1_g = (const float*)d_in[23];
    const float* hbn1_b = (const float*)d_in[24];
    const float* hbn1_m = (const float*)d_in[25];
    const float* hbn1_v = (const float*)d_in[26];
    const float* lin2_W = (const float*)d_in[27];
    const float* lin2_b = (const float*)d_in[28];
    const float* hbn2_g = (const float*)d_in[29];
    const float* hbn2_b = (const float*)d_in[30];
    const float* hbn2_m = (const float*)d_in[31];
    const float* hbn2_v = (const float*)d_in[32];
    const float* lin3_W = (const float*)d_in[33];
    const float* lin3_b = (const float*)d_in[34];

    const int E = in_sizes[1] / 2;
    const int* src = eidx;
    const int* dst = eidx + E;

    char* ws = (char*)d_ws;
    const size_t Y0_OFF  = 0;
    const size_t Z_OFF   = (size_t)NNODES * CH * 4;          // 17,563,648
    const size_t DEG_OFF = Z_OFF + (size_t)NG * 128 * 4;
    const size_t TKT_OFF = DEG_OFF + (size_t)NNODES * 4;     // ticket right after deg
    const size_t RP_OFF  = TKT_OFF + 64;
    const size_t EB_OFF  = RP_OFF + (size_t)(NG * RPS + 4) * 4;

    float* y0    = (float*)(ws + Y0_OFF);
    float* z     = (float*)(ws + Z_OFF);
    int* deg     = (int*)(ws + DEG_OFF);   // degree -> cursor
    int* ticket  = (int*)(ws + TKT_OFF);
    int* row_ptr = (int*)(ws + RP_OFF);
    int* ebuf    = (int*)(ws + EB_OFF);

    k_gemm1<<<NNODES / 128, 128, 0, stream>>>(x, W1_0, y0);

    hipMemsetAsync(deg, 0, (size_t)NNODES * sizeof(int) + 64, stream);
    k_deg<<<1024, 256, 0, stream>>>(dst, E, deg);
    k_scan_local<<<NG, 512, 0, stream>>>(deg, ticket, row_ptr);
    k_fill<<<1024, 256, 0, stream>>>(src, dst, E, deg, ebuf);

    k_gin<<<NG, 512, 0, stream>>>(y0, row_ptr, ebuf, eps0, b1_0, W2_0, b2_0,
                                  bn0_g, bn0_b, bn0_m, bn0_v, eps1, W1_1, b1_1,
                                  W2_1, b2_1, bn1_g, bn1_b, bn1_m, bn1_v, z);

    k_head<<<NG, 256, 0, stream>>>(z, lin1_W, lin1_b, hbn1_g, hbn1_b, hbn1_m,
                                   hbn1_v, lin2_W, lin2_b, hbn2_g, hbn2_b,
                                   hbn2_m, hbn2_v, lin3_W, lin3_b,
                                   (float*)d_out);
}